// Round 10
// baseline (167.682 us; speedup 1.0000x reference)
//
#include <hip/hip_runtime.h>
#include <math.h>

#define NND 4096
#define SDIM 128
#define HEADS 4
#define D1 64
#define HID 256
#define D2 256
#define C2 1024
#define NP1 (NND + 1)
#define CH 512
#define CHR 8
#define LEAKY 0.2f
#define LN_EPS 1e-5f

typedef __attribute__((ext_vector_type(8))) short bf16x8;
typedef __attribute__((ext_vector_type(4))) float f32x4;
typedef __attribute__((ext_vector_type(8))) unsigned short u16x8;

__device__ __forceinline__ unsigned short f2bf(float f) {
    union { float f; unsigned u; } v; v.f = f;
    unsigned r = v.u + 0x7FFFu + ((v.u >> 16) & 1u);
    return (unsigned short)(r >> 16);
}
__device__ __forceinline__ float bf2f(unsigned short s) {
    union { unsigned u; float f; } v; v.u = ((unsigned)s) << 16; return v.f;
}
__device__ __forceinline__ float wave_sum(float v) {
#pragma unroll
    for (int o = 32; o > 0; o >>= 1) v += __shfl_xor(v, o, 64);
    return v;
}
__device__ __forceinline__ int lower_bound_f(const float* __restrict__ a, float x) {
    int lo = 0, hi = NND;
    while (lo < hi) {
        int mid = (lo + hi) >> 1;
        if (a[mid] < x) lo = mid + 1; else hi = mid;
    }
    return lo;
}
// fragment-linear chunk index: 16-row group, 8-k group
__device__ __forceinline__ int chunk_of(int row, int kg) {
    return ((row >> 4) << 6) + (kg << 4) + (row & 15);
}

#define MM(a, b, c) c = __builtin_amdgcn_mfma_f32_16x16x32_bf16(a, b, c, 0, 0, 0)

// ---------------- sort: rank of 64 elems/block vs all keys (vectorized b128 reads) -------
__device__ __forceinline__ void sort_block(unsigned* key, int* pr,
        const float* __restrict__ et,
        float* __restrict__ ts, int* __restrict__ perm, int h, int e0, int t) {
    for (int p = t; p < NND; p += 256) {
        unsigned u = __float_as_uint(et[h * NND + p]);
        key[p] = (u & 0x80000000u) ? ~u : (u | 0x80000000u);
    }
    if (t < 64) pr[t] = 0;
    __syncthreads();
    const int e = t & 63, sg = t >> 6;
    const int myIdx = e0 + e;
    const unsigned myU = key[myIdx];
    int rank = 0;
    const int kbeg = sg * (NND / 4);
    for (int kb = kbeg; kb < kbeg + NND / 4; kb += 16) {
        uint4 v0 = *(const uint4*)&key[kb];
        uint4 v1 = *(const uint4*)&key[kb + 4];
        uint4 v2 = *(const uint4*)&key[kb + 8];
        uint4 v3 = *(const uint4*)&key[kb + 12];
        unsigned vv[16] = {v0.x, v0.y, v0.z, v0.w, v1.x, v1.y, v1.z, v1.w,
                           v2.x, v2.y, v2.z, v2.w, v3.x, v3.y, v3.z, v3.w};
#pragma unroll
        for (int q = 0; q < 16; q++) {
            unsigned v = vv[q];
            rank += (int)(v < myU) + (int)((v == myU) & ((kb + q) < myIdx));
        }
    }
    atomicAdd(&pr[e], rank);
    __syncthreads();
    if (t < 64) {
        int r = pr[t];
        unsigned u = key[e0 + t];
        float f = (u & 0x80000000u) ? __uint_as_float(u ^ 0x80000000u)
                                    : __uint_as_float(~u);
        ts[h * NND + r] = f;
        perm[h * NND + r] = e0 + t;
    }
}

// ---------------- per-head scalar weight scan ----------------
__device__ __forceinline__ void wprep_block(const float* __restrict__ ts,
        float* __restrict__ SA, float* __restrict__ SB, int h, int t,
        float* swA, float* swB) {
    const int lane = t & 63, w = t >> 6;
    const float tmax = ts[h * NND + NND - 1];
    float a[16], b[16];
    float la = 0.f, lb = 0.f;
    const int kb = t * 16;
#pragma unroll
    for (int q = 0; q < 16; q++) {
        float u = ts[h * NND + kb + q] - tmax;
        a[q] = expf(u); b[q] = expf(LEAKY * u);
        la += a[q]; lb += b[q];
    }
    float sa = la, sb = lb;
#pragma unroll
    for (int o = 1; o < 64; o <<= 1) {
        float ua = __shfl_up(sa, o, 64);
        float ub = __shfl_up(sb, o, 64);
        if (lane >= o) { sa += ua; sb += ub; }
    }
    if (lane == 63) { swA[w] = sa; swB[w] = sb; }
    __syncthreads();
    float baseA = 0.f, baseB = 0.f, totA = 0.f, totB = 0.f;
#pragma unroll
    for (int ww = 0; ww < 4; ww++) {
        float va = swA[ww], vb = swB[ww];
        totA += va; totB += vb;
        if (ww < w) { baseA += va; baseB += vb; }
    }
    float preA = baseA + sa - la;
    float preB = baseB + sb - lb;
#pragma unroll
    for (int q = 0; q < 16; q++) {
        SA[h * NP1 + kb + q] = totA - preA;
        SB[h * NP1 + kb + q] = preB;
        preA += a[q]; preB += b[q];
    }
    if (t == 255) { SA[h * NP1 + NND] = 0.f; SB[h * NP1 + NND] = totB; }
}

// ---------------- k1: gemm1 (fused escore1) | W2 transpose-prep | attn2 fold ------------
__global__ __launch_bounds__(256) void k1_gemm1_prep(
        const float* __restrict__ x, const float* __restrict__ W1,
        const float* __restrict__ attn1,
        const float* __restrict__ W2, const float* __restrict__ attn2,
        float* __restrict__ Wx1, float* __restrict__ es1, float* __restrict__ et1,
        unsigned short* __restrict__ W2h, unsigned short* __restrict__ W2l,
        float* __restrict__ w_es, float* __restrict__ w_et) {
    union SM1 {
        struct {
            unsigned short Ah[256][8], Al[256][8], Bh[256][8], Bl[256][8];
            float esP[2][2][32], etP[2][2][32];
        } g;
        float tile[64][65];
    };
    __shared__ SM1 sm;
    const int bid = blockIdx.x, t = threadIdx.x;
    if (bid < 256) {
        const int lane = t & 63, w = t >> 6;
        const int wm = w >> 1, wn = w & 1;
        const int h = bid & 3, n0 = h * 64, m0 = (bid >> 2) * 64;
        const int fr = lane & 15, kg = lane >> 4;
        const int srow = t & 63, skg = t >> 6;
        const int sc = chunk_of(srow, skg);
        f32x4 z4 = {0.f, 0.f, 0.f, 0.f};
        f32x4 acc[2][2] = {{z4, z4}, {z4, z4}};
        for (int k0 = 0; k0 < SDIM; k0 += 32) {
            {   // A: 8 floats of row srow
                float fv[8];
                *(float4*)&fv[0] = *(const float4*)&x[(size_t)(m0 + srow) * SDIM + k0 + skg * 8];
                *(float4*)&fv[4] = *(const float4*)&x[(size_t)(m0 + srow) * SDIM + k0 + skg * 8 + 4];
                u16x8 ph, pl;
#pragma unroll
                for (int i = 0; i < 8; i++) {
                    unsigned short hi = f2bf(fv[i]);
                    ph[i] = hi; pl[i] = f2bf(fv[i] - bf2f(hi));
                }
                *(u16x8*)&sm.g.Ah[sc][0] = ph;
                *(u16x8*)&sm.g.Al[sc][0] = pl;
            }
            {   // B: 8 k's of column n0+srow
                u16x8 ph, pl;
#pragma unroll
                for (int i = 0; i < 8; i++) {
                    float v = W1[(size_t)(k0 + skg * 8 + i) * HID + n0 + srow];
                    unsigned short hi = f2bf(v);
                    ph[i] = hi; pl[i] = f2bf(v - bf2f(hi));
                }
                *(u16x8*)&sm.g.Bh[sc][0] = ph;
                *(u16x8*)&sm.g.Bl[sc][0] = pl;
            }
            __syncthreads();
            bf16x8 ah0 = *(bf16x8*)&sm.g.Ah[wm * 128 + lane][0];
            bf16x8 ah1 = *(bf16x8*)&sm.g.Ah[wm * 128 + 64 + lane][0];
            bf16x8 al0 = *(bf16x8*)&sm.g.Al[wm * 128 + lane][0];
            bf16x8 al1 = *(bf16x8*)&sm.g.Al[wm * 128 + 64 + lane][0];
            bf16x8 bh0 = *(bf16x8*)&sm.g.Bh[wn * 128 + lane][0];
            bf16x8 bh1 = *(bf16x8*)&sm.g.Bh[wn * 128 + 64 + lane][0];
            bf16x8 bl0 = *(bf16x8*)&sm.g.Bl[wn * 128 + lane][0];
            bf16x8 bl1 = *(bf16x8*)&sm.g.Bl[wn * 128 + 64 + lane][0];
            MM(ah0, bh0, acc[0][0]); MM(ah0, bl0, acc[0][0]); MM(al0, bh0, acc[0][0]);
            MM(ah0, bh1, acc[0][1]); MM(ah0, bl1, acc[0][1]); MM(al0, bh1, acc[0][1]);
            MM(ah1, bh0, acc[1][0]); MM(ah1, bl0, acc[1][0]); MM(al1, bh0, acc[1][0]);
            MM(ah1, bh1, acc[1][1]); MM(ah1, bl1, acc[1][1]); MM(al1, bh1, acc[1][1]);
            __syncthreads();
        }
        const float as0 = attn1[h * 128 + wn * 32 + fr];
        const float as1 = attn1[h * 128 + wn * 32 + 16 + fr];
        const float at0 = attn1[h * 128 + 64 + wn * 32 + fr];
        const float at1 = attn1[h * 128 + 64 + wn * 32 + 16 + fr];
#pragma unroll
        for (int mb = 0; mb < 2; mb++) {
#pragma unroll
            for (int r = 0; r < 4; r++) {
                int row = m0 + wm * 32 + mb * 16 + kg * 4 + r;
#pragma unroll
                for (int nb = 0; nb < 2; nb++)
                    Wx1[(size_t)row * HID + n0 + wn * 32 + nb * 16 + fr] = acc[mb][nb][r];
                float ve = acc[mb][0][r] * as0 + acc[mb][1][r] * as1;
                float vt = acc[mb][0][r] * at0 + acc[mb][1][r] * at1;
#pragma unroll
                for (int msk = 1; msk < 16; msk <<= 1) {
                    ve += __shfl_xor(ve, msk, 64);
                    vt += __shfl_xor(vt, msk, 64);
                }
                if (fr == 0) {
                    sm.g.esP[wm][wn][mb * 16 + kg * 4 + r] = ve;
                    sm.g.etP[wm][wn][mb * 16 + kg * 4 + r] = vt;
                }
            }
        }
        __syncthreads();
        if (t < 64) {
            int wmm = t >> 5, ri = t & 31;
            es1[h * NND + m0 + t] = sm.g.esP[wmm][0][ri] + sm.g.esP[wmm][1][ri];
            et1[h * NND + m0 + t] = sm.g.etP[wmm][0][ri] + sm.g.etP[wmm][1][ri];
        }
    } else if (bid < 320) {
        // W2 (256x1024) -> W2h/W2l [n][k], 64x64 LDS transpose tile, coalesced both sides
        const int tb = bid - 256;            // 0..63
        const int tk = tb & 3, tn = tb >> 2; // 4 K-tiles x 16 N-tiles
#pragma unroll
        for (int q = 0; q < 16; q++) {
            int idx = q * 256 + t;
            int kr = idx >> 6, nc = idx & 63;
            sm.tile[kr][nc] = W2[(size_t)(tk * 64 + kr) * C2 + tn * 64 + nc];
        }
        __syncthreads();
#pragma unroll
        for (int q = 0; q < 16; q++) {
            int idx = q * 256 + t;
            int nr = idx >> 6, kc = idx & 63;
            float v = sm.tile[kc][nr];
            unsigned short hi = f2bf(v);
            size_t o = (size_t)(tn * 64 + nr) * HID + tk * 64 + kc;
            W2h[o] = hi;
            W2l[o] = f2bf(v - bf2f(hi));
        }
    } else {
        int g = (bid - 320) * 4 + (t >> 6);
        int lane = t & 63;
        int k = g & 255, hs = g >> 8, h = hs >> 1, sel = hs & 1;
        float acc = 0.f;
#pragma unroll
        for (int qq = 0; qq < 4; qq++)
            acc += W2[(size_t)k * C2 + h * 256 + qq * 64 + lane] *
                   attn2[h * 512 + sel * 256 + qq * 64 + lane];
        acc = wave_sum(acc);
        if (lane == 0) {
            if (sel) w_et[h * 256 + k] = acc;
            else     w_es[h * 256 + k] = acc;
        }
    }
}

// ---------------- k2: sort (layer 1) ----------------
__global__ __launch_bounds__(256) void k2_sort(const float* __restrict__ et,
        float* __restrict__ ts, int* __restrict__ perm) {
    __shared__ unsigned key[NND];
    __shared__ int pr[64];
    const int bid = blockIdx.x, t = threadIdx.x;
    sort_block(key, pr, et, ts, perm, bid >> 6, (bid & 63) * 64, t);
}

// ---------------- k3: layer-1 scan p1 (4h x 64d) + wprep1 ----------------
__global__ __launch_bounds__(256) void k3_scan1_p1(const float* __restrict__ Wx1,
        const float* __restrict__ ts1, const int* __restrict__ perm1,
        float* __restrict__ cTA, float* __restrict__ cTB,
        float* __restrict__ SA, float* __restrict__ SB) {
    __shared__ float swA[4], swB[4];
    const int bid = blockIdx.x, t = threadIdx.x;
    if (bid >= CH) { wprep_block(ts1, SA, SB, bid - CH, t, swA, swB); return; }
    const int h = t >> 6, d = t & 63;
    const int k0 = bid * CHR;
    const float tmax = ts1[h * NND + NND - 1];
    float aA = 0.f, aB = 0.f;
#pragma unroll
    for (int r = 0; r < CHR; r++) {
        float u = ts1[h * NND + k0 + r] - tmax;
        float wa = expf(u), wb = expf(LEAKY * u);
        int j = perm1[h * NND + k0 + r];
        float v = Wx1[(size_t)j * HID + h * D1 + d];
        aA += wa * v; aB += wb * v;
    }
    cTA[(h * CH + bid) * D1 + d] = aA;
    cTB[(h * CH + bid) * D1 + d] = aB;
}

// ---------------- p2: wave-parallel exclusive scan of chunk totals (in place) ------------
__global__ __launch_bounds__(256) void k_scan_p2(float* __restrict__ cTA,
        float* __restrict__ cTB, float* __restrict__ TotA, float* __restrict__ TotB,
        int logD) {
    const int t = threadIdx.x;
    const int lane = t & 63, w = t >> 6;
    const int D = 1 << logD;
    const int col = blockIdx.x * 4 + w;
    const int h = col >> logD, d = col & (D - 1);
    const size_t base = (size_t)h * CH * D + d;
    float vA[8], vB[8];
#pragma unroll
    for (int q = 0; q < 8; q++) {
        size_t o = base + (size_t)(lane * 8 + q) * D;
        vA[q] = cTA[o];
        vB[q] = cTB[o];
    }
    float laA = 0.f, laB = 0.f;
#pragma unroll
    for (int q = 0; q < 8; q++) { laA += vA[q]; laB += vB[q]; }
    float sA = laA, sB = laB;
#pragma unroll
    for (int o = 1; o < 64; o <<= 1) {
        float uA = __shfl_up(sA, o, 64);
        float uB = __shfl_up(sB, o, 64);
        if (lane >= o) { sA += uA; sB += uB; }
    }
    float totA = __shfl(sA, 63, 64);
    float totB = __shfl(sB, 63, 64);
    float runA = sA - laA, runB = sB - laB;
#pragma unroll
    for (int q = 0; q < 8; q++) {
        size_t o = base + (size_t)(lane * 8 + q) * D;
        float tA = vA[q], tB = vB[q];
        cTA[o] = runA;
        cTB[o] = runB;
        runA += tA; runB += tB;
    }
    if (lane == 0) {
        TotA[h * D + d] = totA;
        TotB[h * D + d] = totB;
    }
}

// ---------------- k5: layer-1 scan p3 ----------------
__global__ __launch_bounds__(256) void k5_scan1_p3(const float* __restrict__ Wx1,
        const float* __restrict__ ts1, const int* __restrict__ perm1,
        const float* __restrict__ cTA, const float* __restrict__ cTB,
        const float* __restrict__ TotA,
        float* __restrict__ A, float* __restrict__ B) {
    const int ch = blockIdx.x, t = threadIdx.x;
    const int h = t >> 6, d = t & 63;
    const float tmax = ts1[h * NND + NND - 1];
    float runA = cTA[(h * CH + ch) * D1 + d];
    float runB = cTB[(h * CH + ch) * D1 + d];
    const float totA = TotA[h * D1 + d];
    const int k0 = ch * CHR;
    float v[CHR], wa[CHR], wb[CHR];
#pragma unroll
    for (int r = 0; r < CHR; r++) {
        float u = ts1[h * NND + k0 + r] - tmax;
        wa[r] = expf(u); wb[r] = expf(LEAKY * u);
        int j = perm1[h * NND + k0 + r];
        v[r] = Wx1[(size_t)j * HID + h * D1 + d];
    }
#pragma unroll
    for (int r = 0; r < CHR; r++) {
        size_t o = ((size_t)(h * NP1 + k0 + r)) * D1 + d;
        A[o] = totA - runA;
        B[o] = runB;
        runA += wa[r] * v[r];
        runB += wb[r] * v[r];
    }
    if (ch == CH - 1) {
        size_t o = ((size_t)(h * NP1 + NND)) * D1 + d;
        A[o] = totA - runA;
        B[o] = runB;
    }
}

// ---------------- k6: lookup1 -> h1 (split bf16) + fused escore2 (per-wave head) ---------
__global__ __launch_bounds__(256) void k6_lookup1(const float* __restrict__ es,
        const float* __restrict__ ts,
        const float* __restrict__ A, const float* __restrict__ Bv,
        const float* __restrict__ SA, const float* __restrict__ SB,
        const float* __restrict__ w_es, const float* __restrict__ w_et,
        unsigned short* __restrict__ h1h, unsigned short* __restrict__ h1l,
        float* __restrict__ es2, float* __restrict__ et2) {
    __shared__ float hbuf[256];
    const int i = blockIdx.x, t = threadIdx.x;
    const int h = t >> 6, d = t & 63;
    const int lane = t & 63, wid = t >> 6;
    float c = es[h * NND + i];
    float tmax = ts[h * NND + NND - 1];
    float s = c + tmax;
    float m = (s >= 0.f) ? s : LEAKY * s;
    float al = expf(s - m);
    float be = expf(LEAKY * s - m);
    int k = lower_bound_f(ts + h * NND, -c);
    size_t o = ((size_t)(h * NP1 + k)) * D1 + d;
    float num = al * A[o] + be * Bv[o];
    float den = al * SA[h * NP1 + k] + be * SB[h * NP1 + k];
    float val = num / den;
    float hv = (val > 0.f) ? val : expm1f(val);
    unsigned short hh = f2bf(hv);
    h1h[i * HID + t] = hh;
    h1l[i * HID + t] = f2bf(hv - bf2f(hh));
    hbuf[t] = hv;
    __syncthreads();
    float4 hv4 = *(const float4*)&hbuf[lane * 4];
    float4 we4 = *(const float4*)&w_es[wid * HID + lane * 4];
    float4 wt4 = *(const float4*)&w_et[wid * HID + lane * 4];
    float pes = hv4.x * we4.x + hv4.y * we4.y + hv4.z * we4.z + hv4.w * we4.w;
    float pet = hv4.x * wt4.x + hv4.y * wt4.y + hv4.z * wt4.z + hv4.w * wt4.w;
    pes = wave_sum(pes);
    pet = wave_sum(pet);
    if (lane == 0) {
        es2[wid * NND + i] = pes;
        et2[wid * NND + i] = pet;
    }
}

// ---------------- k7: gemm2 128x64 tile (reg prefetch) | sort2 ----------------
__global__ __launch_bounds__(256) void k7_gemm2_sort2(
        const unsigned short* __restrict__ h1h, const unsigned short* __restrict__ h1l,
        const unsigned short* __restrict__ W2h, const unsigned short* __restrict__ W2l,
        float* __restrict__ Wx2,
        const float* __restrict__ et2, float* __restrict__ ts2, int* __restrict__ perm2) {
    union SM7 {
        struct { unsigned short Ah[512][8], Al[512][8], Bh[256][8], Bl[256][8]; } g;
        struct { unsigned key[NND]; int pr[64]; } s;
    };
    __shared__ SM7 sm;
    const int bid = blockIdx.x, t = threadIdx.x;
    if (bid >= 512) {
        sort_block(sm.s.key, sm.s.pr, et2, ts2, perm2,
                   (bid - 512) >> 6, ((bid - 512) & 63) * 64, t);
        return;
    }
    const int lane = t & 63, w = t >> 6;
    const int n0 = (bid & 15) * 64, m0 = (bid >> 4) * 128;
    const int fr = lane & 15, kg = lane >> 4;
    const int srow = t & 63, skg = t >> 6;
    f32x4 z4 = {0.f, 0.f, 0.f, 0.f};
    f32x4 acc[2][4] = {{z4, z4, z4, z4}, {z4, z4, z4, z4}};
    u16x8 rAh[2], rAl[2], rBh, rBl;
    auto load_step = [&](int k0) {
#pragma unroll
        for (int rr = 0; rr < 2; rr++) {
            rAh[rr] = *(const u16x8*)&h1h[(size_t)(m0 + rr * 64 + srow) * HID + k0 + skg * 8];
            rAl[rr] = *(const u16x8*)&h1l[(size_t)(m0 + rr * 64 + srow) * HID + k0 + skg * 8];
        }
        rBh = *(const u16x8*)&W2h[(size_t)(n0 + srow) * HID + k0 + skg * 8];
        rBl = *(const u16x8*)&W2l[(size_t)(n0 + srow) * HID + k0 + skg * 8];
    };
    load_step(0);
    for (int k0 = 0; k0 < HID; k0 += 32) {
#pragma unroll
        for (int rr = 0; rr < 2; rr++) {
            int c = chunk_of(rr * 64 + srow, skg);
            *(u16x8*)&sm.g.Ah[c][0] = rAh[rr];
            *(u16x8*)&sm.g.Al[c][0] = rAl[rr];
        }
        int cb = chunk_of(srow, skg);
        *(u16x8*)&sm.g.Bh[cb][0] = rBh;
        *(u16x8*)&sm.g.Bl[cb][0] = rBl;
        __syncthreads();
        if (k0 + 32 < HID) load_step(k0 + 32);   // overlap with frag reads + MFMA
        bf16x8 ah[2], al[2], bh[4], bl[4];
#pragma unroll
        for (int mb = 0; mb < 2; mb++) {
            ah[mb] = *(bf16x8*)&sm.g.Ah[w * 128 + mb * 64 + lane][0];
            al[mb] = *(bf16x8*)&sm.g.Al[w * 128 + mb * 64 + lane][0];
        }
#pragma unroll
        for (int nb = 0; nb < 4; nb++) {
            bh[nb] = *(bf16x8*)&sm.g.Bh[nb * 64 + lane][0];
            bl[nb] = *(bf16x8*)&sm.g.Bl[nb * 64 + lane][0];
        }
#pragma unroll
        for (int mb = 0; mb < 2; mb++)
#pragma unroll
            for (int nb = 0; nb < 4; nb++) {
                MM(ah[mb], bh[nb], acc[mb][nb]);
                MM(ah[mb], bl[nb], acc[mb][nb]);
                MM(al[mb], bh[nb], acc[mb][nb]);
            }
        __syncthreads();
    }
#pragma unroll
    for (int mb = 0; mb < 2; mb++)
#pragma unroll
        for (int r = 0; r < 4; r++) {
            int row = m0 + w * 32 + mb * 16 + kg * 4 + r;
#pragma unroll
            for (int nb = 0; nb < 4; nb++)
                Wx2[(size_t)row * C2 + n0 + nb * 16 + fr] = acc[mb][nb][r];
        }
}

// ---------------- k8: layer-2 scan p1 + wprep2 ----------------
__global__ __launch_bounds__(256) void k8_scan2_p1(const float* __restrict__ Wx2,
        const float* __restrict__ ts2, const int* __restrict__ perm2,
        float* __restrict__ cTA, float* __restrict__ cTB,
        float* __restrict__ SA, float* __restrict__ SB) {
    __shared__ float swA[4], swB[4];
    const int bid = blockIdx.x, t = threadIdx.x;
    if (bid >= 2048) { wprep_block(ts2, SA, SB, bid - 2048, t, swA, swB); return; }
    const int ch = bid & (CH - 1), h = bid >> 9;
    const int d = t, k0 = ch * CHR;
    const float tmax = ts2[h * NND + NND - 1];
    float aA = 0.f, aB = 0.f;
#pragma unroll
    for (int r = 0; r < CHR; r++) {
        float u = ts2[h * NND + k0 + r] - tmax;
        float wa = expf(u), wb = expf(LEAKY * u);
        int j = perm2[h * NND + k0 + r];
        float v = Wx2[(size_t)j * C2 + h * D2 + d];
        aA += wa * v; aB += wb * v;
    }
    cTA[(h * CH + ch) * D2 + d] = aA;
    cTB[(h * CH + ch) * D2 + d] = aB;
}

// ---------------- k10: layer-2 scan p3 ----------------
__global__ __launch_bounds__(256) void k10_scan2_p3(const float* __restrict__ Wx2,
        const float* __restrict__ ts2, const int* __restrict__ perm2,
        const float* __restrict__ cTA, const float* __restrict__ cTB,
        const float* __restrict__ TotA,
        float* __restrict__ A, float* __restrict__ B) {
    const int bid = blockIdx.x, t = threadIdx.x;
    const int ch = bid & (CH - 1), h = bid >> 9;
    const int d = t;
    const float tmax = ts2[h * NND + NND - 1];
    float runA = cTA[(h * CH + ch) * D2 + d];
    float runB = cTB[(h * CH + ch) * D2 + d];
    const float totA = TotA[h * D2 + d];
    const int k0 = ch * CHR;
    float v[CHR], wa[CHR], wb[CHR];
#pragma unroll
    for (int r = 0; r < CHR; r++) {
        float u = ts2[h * NND + k0 + r] - tmax;
        wa[r] = expf(u); wb[r] = expf(LEAKY * u);
        int j = perm2[h * NND + k0 + r];
        v[r] = Wx2[(size_t)j * C2 + h * D2 + d];
    }
#pragma unroll
    for (int r = 0; r < CHR; r++) {
        size_t o = ((size_t)(h * NP1 + k0 + r)) * D2 + d;
        A[o] = totA - runA;
        B[o] = runB;
        runA += wa[r] * v[r];
        runB += wb[r] * v[r];
    }
    if (ch == CH - 1) {
        size_t o = ((size_t)(h * NP1 + NND)) * D2 + d;
        A[o] = totA - runA;
        B[o] = runB;
    }
}

// ---------------- k11: lookup2 (head-mean + ELU + LayerNorm) ----------------
__global__ __launch_bounds__(256) void k11_lookup2(const float* __restrict__ es,
        const float* __restrict__ ts,
        const float* __restrict__ A, const float* __restrict__ B,
        const float* __restrict__ SA, const float* __restrict__ SB,
        const float* __restrict__ gamma, const float* __restrict__ betap,
        float* __restrict__ out) {
    __shared__ float red[4];
    const int i = blockIdx.x;
    const int t = threadIdx.x;
    const int wid = t >> 6, lane = t & 63;
    float acc = 0.f;
#pragma unroll
    for (int h = 0; h < HEADS; h++) {
        float c = es[h * NND + i];
        float tmax = ts[h * NND + NND - 1];
        float s = c + tmax;
        float m = (s >= 0.f) ? s : LEAKY * s;
        float al = expf(s - m);
        float be = expf(LEAKY * s - m);
        int k = lower_bound_f(ts + h * NND, -c);
        size_t o = ((size_t)(h * NP1 + k)) * D2 + t;
        float num = al * A[o] + be * B[o];
        float den = al * SA[h * NP1 + k] + be * SB[h * NP1 + k];
        acc += num / den;
    }
    acc *= 0.25f;
    float xv = (acc > 0.f) ? acc : expm1f(acc);
    float sv = wave_sum(xv);
    if (lane == 0) red[wid] = sv;
    __syncthreads();
    float mu = (red[0] + red[1] + red[2] + red[3]) * (1.f / 256.f);
    __syncthreads();
    float dv = xv - mu;
    float s2 = wave_sum(dv * dv);
    if (lane == 0) red[wid] = s2;
    __syncthreads();
    float var = (red[0] + red[1] + red[2] + red[3]) * (1.f / 256.f);
    out[i * D2 + t] = gamma[t] * dv * rsqrtf(var + LN_EPS) + betap[t];
}

extern "C" void kernel_launch(void* const* d_in, const int* in_sizes, int n_in,
                              void* d_out, int out_size, void* d_ws, size_t ws_size,
                              hipStream_t stream) {
    const float* x     = (const float*)d_in[0];
    const float* W1    = (const float*)d_in[1];
    const float* attn1 = (const float*)d_in[2];
    const float* W2    = (const float*)d_in[3];
    const float* attn2 = (const float*)d_in[4];
    const float* gamma = (const float*)d_in[5];
    const float* betap = (const float*)d_in[6];
    float* out = (float*)d_out;

    char* ws = (char*)d_ws;
    size_t off = 0;
    auto alloc = [&](size_t nbytes) -> void* {
        void* p = (void*)(ws + off);
        off += (nbytes + 255) & ~(size_t)255;
        return p;
    };

    float* Wx1 = (float*)alloc((size_t)NND * HID * 4);
    float* Wx2 = (float*)alloc((size_t)NND * C2 * 4);
    unsigned short* h1h = (unsigned short*)alloc((size_t)NND * HID * 2);
    unsigned short* h1l = (unsigned short*)alloc((size_t)NND * HID * 2);
    float* es1 = (float*)alloc((size_t)HEADS * NND * 4);
    float* et1 = (float*)alloc((size_t)HEADS * NND * 4);
    float* es2 = (float*)alloc((size_t)HEADS * NND * 4);
    float* et2 = (float*)alloc((size_t)HEADS * NND * 4);
    float* ts1 = (float*)alloc((size_t)HEADS * NND * 4);
    float* ts2 = (float*)alloc((size_t)HEADS * NND * 4);
    int* perm1 = (int*)alloc((size_t)HEADS * NND * 4);
    int* perm2 = (int*)alloc((size_t)HEADS * NND * 4);
    float* A   = (float*)alloc((size_t)HEADS * NP1 * D2 * 4);
    float* B   = (float*)alloc((size_t)HEADS * NP1 * D2 * 4);
    float* SA  = (float*)alloc((size_t)HEADS * NP1 * 4);
    float* SB  = (float*)alloc((size_t)HEADS * NP1 * 4);
    float* cTA = (float*)alloc((size_t)HEADS * CH * D2 * 4);
    float* cTB = (float*)alloc((size_t)HEADS * CH * D2 * 4);
    float* TotA = (float*)alloc((size_t)HEADS * D2 * 4);
    float* TotB = (float*)alloc((size_t)HEADS * D2 * 4);
    unsigned short* W2h = (unsigned short*)alloc((size_t)262144 * 2);
    unsigned short* W2l = (unsigned short*)alloc((size_t)262144 * 2);
    float* w_es = (float*)alloc((size_t)HEADS * HID * 4);
    float* w_et = (float*)alloc((size_t)HEADS * HID * 4);
    (void)ws_size; (void)in_sizes; (void)n_in; (void)out_size;

    // ---- layer 1 ----
    k1_gemm1_prep<<<832, 256, 0, stream>>>(x, W1, attn1, W2, attn2,
                                           Wx1, es1, et1, W2h, W2l, w_es, w_et);
    k2_sort<<<256, 256, 0, stream>>>(et1, ts1, perm1);
    k3_scan1_p1<<<CH + 4, 256, 0, stream>>>(Wx1, ts1, perm1, cTA, cTB, SA, SB);
    k_scan_p2<<<64, 256, 0, stream>>>(cTA, cTB, TotA, TotB, 6);
    k5_scan1_p3<<<CH, 256, 0, stream>>>(Wx1, ts1, perm1, cTA, cTB, TotA, A, B);
    k6_lookup1<<<NND, 256, 0, stream>>>(es1, ts1, A, B, SA, SB, w_es, w_et,
                                        h1h, h1l, es2, et2);

    // ---- layer 2 ----
    k7_gemm2_sort2<<<768, 256, 0, stream>>>(h1h, h1l, W2h, W2l, Wx2, et2, ts2, perm2);
    k8_scan2_p1<<<2052, 256, 0, stream>>>(Wx2, ts2, perm2, cTA, cTB, SA, SB);
    k_scan_p2<<<256, 256, 0, stream>>>(cTA, cTB, TotA, TotB, 8);
    k10_scan2_p3<<<2048, 256, 0, stream>>>(Wx2, ts2, perm2, cTA, cTB, TotA, A, B);
    k11_lookup2<<<NND, 256, 0, stream>>>(es2, ts2, A, B, SA, SB, gamma, betap, out);
}

// Round 11
// 155.772 us; speedup vs baseline: 1.0765x; 1.0765x over previous
//
#include <hip/hip_runtime.h>
#include <math.h>

#define NND 4096
#define SDIM 128
#define HEADS 4
#define D1 64
#define HID 256
#define D2 256
#define C2 1024
#define NP1 (NND + 1)
#define CH 512
#define CHR 8
#define LEAKY 0.2f
#define LN_EPS 1e-5f

typedef __attribute__((ext_vector_type(8))) short bf16x8;
typedef __attribute__((ext_vector_type(4))) float f32x4;
typedef __attribute__((ext_vector_type(8))) unsigned short u16x8;

__device__ __forceinline__ unsigned short f2bf(float f) {
    union { float f; unsigned u; } v; v.f = f;
    unsigned r = v.u + 0x7FFFu + ((v.u >> 16) & 1u);
    return (unsigned short)(r >> 16);
}
__device__ __forceinline__ float bf2f(unsigned short s) {
    union { unsigned u; float f; } v; v.u = ((unsigned)s) << 16; return v.f;
}
__device__ __forceinline__ float wave_sum(float v) {
#pragma unroll
    for (int o = 32; o > 0; o >>= 1) v += __shfl_xor(v, o, 64);
    return v;
}
__device__ __forceinline__ int lower_bound_f(const float* __restrict__ a, float x) {
    int lo = 0, hi = NND;
    while (lo < hi) {
        int mid = (lo + hi) >> 1;
        if (a[mid] < x) lo = mid + 1; else hi = mid;
    }
    return lo;
}
// fragment-linear chunk index for gemm1: 16-row group, 8-k group
__device__ __forceinline__ int chunk_of(int row, int kg) {
    return ((row >> 4) << 6) + (kg << 4) + (row & 15);
}

#define MM(a, b, c) c = __builtin_amdgcn_mfma_f32_16x16x32_bf16(a, b, c, 0, 0, 0)

// ---------------- sort: rank of 64 elems/block vs all keys (vectorized b128 reads) -------
__device__ __forceinline__ void sort_block(unsigned* key, int* pr,
        const float* __restrict__ et,
        float* __restrict__ ts, int* __restrict__ perm, int h, int e0, int t) {
    for (int p = t; p < NND; p += 256) {
        unsigned u = __float_as_uint(et[h * NND + p]);
        key[p] = (u & 0x80000000u) ? ~u : (u | 0x80000000u);
    }
    if (t < 64) pr[t] = 0;
    __syncthreads();
    const int e = t & 63, sg = t >> 6;
    const int myIdx = e0 + e;
    const unsigned myU = key[myIdx];
    int rank = 0;
    const int kbeg = sg * (NND / 4);
    for (int kb = kbeg; kb < kbeg + NND / 4; kb += 16) {
        uint4 v0 = *(const uint4*)&key[kb];
        uint4 v1 = *(const uint4*)&key[kb + 4];
        uint4 v2 = *(const uint4*)&key[kb + 8];
        uint4 v3 = *(const uint4*)&key[kb + 12];
        unsigned vv[16] = {v0.x, v0.y, v0.z, v0.w, v1.x, v1.y, v1.z, v1.w,
                           v2.x, v2.y, v2.z, v2.w, v3.x, v3.y, v3.z, v3.w};
#pragma unroll
        for (int q = 0; q < 16; q++) {
            unsigned v = vv[q];
            rank += (int)(v < myU) + (int)((v == myU) & ((kb + q) < myIdx));
        }
    }
    atomicAdd(&pr[e], rank);
    __syncthreads();
    if (t < 64) {
        int r = pr[t];
        unsigned u = key[e0 + t];
        float f = (u & 0x80000000u) ? __uint_as_float(u ^ 0x80000000u)
                                    : __uint_as_float(~u);
        ts[h * NND + r] = f;
        perm[h * NND + r] = e0 + t;
    }
}

// ---------------- per-head scalar weight scan ----------------
__device__ __forceinline__ void wprep_block(const float* __restrict__ ts,
        float* __restrict__ SA, float* __restrict__ SB, int h, int t,
        float* swA, float* swB) {
    const int lane = t & 63, w = t >> 6;
    const float tmax = ts[h * NND + NND - 1];
    float a[16], b[16];
    float la = 0.f, lb = 0.f;
    const int kb = t * 16;
#pragma unroll
    for (int q = 0; q < 16; q++) {
        float u = ts[h * NND + kb + q] - tmax;
        a[q] = expf(u); b[q] = expf(LEAKY * u);
        la += a[q]; lb += b[q];
    }
    float sa = la, sb = lb;
#pragma unroll
    for (int o = 1; o < 64; o <<= 1) {
        float ua = __shfl_up(sa, o, 64);
        float ub = __shfl_up(sb, o, 64);
        if (lane >= o) { sa += ua; sb += ub; }
    }
    if (lane == 63) { swA[w] = sa; swB[w] = sb; }
    __syncthreads();
    float baseA = 0.f, baseB = 0.f, totA = 0.f, totB = 0.f;
#pragma unroll
    for (int ww = 0; ww < 4; ww++) {
        float va = swA[ww], vb = swB[ww];
        totA += va; totB += vb;
        if (ww < w) { baseA += va; baseB += vb; }
    }
    float preA = baseA + sa - la;
    float preB = baseB + sb - lb;
#pragma unroll
    for (int q = 0; q < 16; q++) {
        SA[h * NP1 + kb + q] = totA - preA;
        SB[h * NP1 + kb + q] = preB;
        preA += a[q]; preB += b[q];
    }
    if (t == 255) { SA[h * NP1 + NND] = 0.f; SB[h * NP1 + NND] = totB; }
}

// ---------------- k1: gemm1 (fused escore1) | W2 panel-prep | attn2 fold ------------
__global__ __launch_bounds__(256) void k1_gemm1_prep(
        const float* __restrict__ x, const float* __restrict__ W1,
        const float* __restrict__ attn1,
        const float* __restrict__ W2, const float* __restrict__ attn2,
        float* __restrict__ Wx1, float* __restrict__ es1, float* __restrict__ et1,
        unsigned short* __restrict__ W2p,
        float* __restrict__ w_es, float* __restrict__ w_et) {
    union SM1 {
        struct {
            unsigned short Ah[256][8], Al[256][8], Bh[256][8], Bl[256][8];
            float esP[2][2][32], etP[2][2][32];
        } g;
        float tile[64][65];
    };
    __shared__ SM1 sm;
    const int bid = blockIdx.x, t = threadIdx.x;
    if (bid < 256) {
        const int lane = t & 63, w = t >> 6;
        const int wm = w >> 1, wn = w & 1;
        const int h = bid & 3, n0 = h * 64, m0 = (bid >> 2) * 64;
        const int fr = lane & 15, kg = lane >> 4;
        // A-staging mapping (coalesced: 4 lanes cover one 128B row-segment)
        const int arow = t >> 2, akg = t & 3;
        const int ac = chunk_of(arow, akg);
        // B-staging mapping (coalesced across n)
        const int brow = t & 63, bkg = t >> 6;
        const int bc = chunk_of(brow, bkg);
        f32x4 z4 = {0.f, 0.f, 0.f, 0.f};
        f32x4 acc[2][2] = {{z4, z4}, {z4, z4}};
        for (int k0 = 0; k0 < SDIM; k0 += 32) {
            {   // A: 8 floats of row arow, cols k0+akg*8..+7
                float fv[8];
                *(float4*)&fv[0] = *(const float4*)&x[(size_t)(m0 + arow) * SDIM + k0 + akg * 8];
                *(float4*)&fv[4] = *(const float4*)&x[(size_t)(m0 + arow) * SDIM + k0 + akg * 8 + 4];
                u16x8 ph, pl;
#pragma unroll
                for (int i = 0; i < 8; i++) {
                    unsigned short hi = f2bf(fv[i]);
                    ph[i] = hi; pl[i] = f2bf(fv[i] - bf2f(hi));
                }
                *(u16x8*)&sm.g.Ah[ac][0] = ph;
                *(u16x8*)&sm.g.Al[ac][0] = pl;
            }
            {   // B: 8 k's of column n0+brow (coalesced per k across lanes)
                u16x8 ph, pl;
#pragma unroll
                for (int i = 0; i < 8; i++) {
                    float v = W1[(size_t)(k0 + bkg * 8 + i) * HID + n0 + brow];
                    unsigned short hi = f2bf(v);
                    ph[i] = hi; pl[i] = f2bf(v - bf2f(hi));
                }
                *(u16x8*)&sm.g.Bh[bc][0] = ph;
                *(u16x8*)&sm.g.Bl[bc][0] = pl;
            }
            __syncthreads();
            bf16x8 ah0 = *(bf16x8*)&sm.g.Ah[wm * 128 + lane][0];
            bf16x8 ah1 = *(bf16x8*)&sm.g.Ah[wm * 128 + 64 + lane][0];
            bf16x8 al0 = *(bf16x8*)&sm.g.Al[wm * 128 + lane][0];
            bf16x8 al1 = *(bf16x8*)&sm.g.Al[wm * 128 + 64 + lane][0];
            bf16x8 bh0 = *(bf16x8*)&sm.g.Bh[wn * 128 + lane][0];
            bf16x8 bh1 = *(bf16x8*)&sm.g.Bh[wn * 128 + 64 + lane][0];
            bf16x8 bl0 = *(bf16x8*)&sm.g.Bl[wn * 128 + lane][0];
            bf16x8 bl1 = *(bf16x8*)&sm.g.Bl[wn * 128 + 64 + lane][0];
            MM(ah0, bh0, acc[0][0]); MM(ah0, bl0, acc[0][0]); MM(al0, bh0, acc[0][0]);
            MM(ah0, bh1, acc[0][1]); MM(ah0, bl1, acc[0][1]); MM(al0, bh1, acc[0][1]);
            MM(ah1, bh0, acc[1][0]); MM(ah1, bl0, acc[1][0]); MM(al1, bh0, acc[1][0]);
            MM(ah1, bh1, acc[1][1]); MM(ah1, bl1, acc[1][1]); MM(al1, bh1, acc[1][1]);
            __syncthreads();
        }
        const float as0 = attn1[h * 128 + wn * 32 + fr];
        const float as1 = attn1[h * 128 + wn * 32 + 16 + fr];
        const float at0 = attn1[h * 128 + 64 + wn * 32 + fr];
        const float at1 = attn1[h * 128 + 64 + wn * 32 + 16 + fr];
#pragma unroll
        for (int mb = 0; mb < 2; mb++) {
#pragma unroll
            for (int r = 0; r < 4; r++) {
                int row = m0 + wm * 32 + mb * 16 + kg * 4 + r;
#pragma unroll
                for (int nb = 0; nb < 2; nb++)
                    Wx1[(size_t)row * HID + n0 + wn * 32 + nb * 16 + fr] = acc[mb][nb][r];
                float ve = acc[mb][0][r] * as0 + acc[mb][1][r] * as1;
                float vt = acc[mb][0][r] * at0 + acc[mb][1][r] * at1;
#pragma unroll
                for (int msk = 1; msk < 16; msk <<= 1) {
                    ve += __shfl_xor(ve, msk, 64);
                    vt += __shfl_xor(vt, msk, 64);
                }
                if (fr == 0) {
                    sm.g.esP[wm][wn][mb * 16 + kg * 4 + r] = ve;
                    sm.g.etP[wm][wn][mb * 16 + kg * 4 + r] = vt;
                }
            }
        }
        __syncthreads();
        if (t < 64) {
            int wmm = t >> 5, ri = t & 31;
            es1[h * NND + m0 + t] = sm.g.esP[wmm][0][ri] + sm.g.esP[wmm][1][ri];
            et1[h * NND + m0 + t] = sm.g.etP[wmm][0][ri] + sm.g.etP[wmm][1][ri];
        }
    } else if (bid < 320) {
        // W2 (256x1024) -> bf16 k-panels W2p[kgrp][1024][8], via 64x64 LDS transpose tile
        const int tb = bid - 256;            // 0..63
        const int tk = tb & 3, tn = tb >> 2; // 4 K-tiles x 16 N-tiles
#pragma unroll
        for (int q = 0; q < 16; q++) {
            int idx = q * 256 + t;
            int kr = idx >> 6, nc = idx & 63;
            sm.tile[kr][nc] = W2[(size_t)(tk * 64 + kr) * C2 + tn * 64 + nc];
        }
        __syncthreads();
#pragma unroll
        for (int q = 0; q < 16; q++) {
            int idx = q * 256 + t;
            int nr = idx >> 6, kc = idx & 63;
            float v = sm.tile[kc][nr];
            int kglob = tk * 64 + kc;
            size_t o = ((size_t)(kglob >> 3) * C2 + tn * 64 + nr) * 8 + (kglob & 7);
            W2p[o] = f2bf(v);
        }
    } else {
        int g = (bid - 320) * 4 + (t >> 6);
        int lane = t & 63;
        int k = g & 255, hs = g >> 8, h = hs >> 1, sel = hs & 1;
        float acc = 0.f;
#pragma unroll
        for (int qq = 0; qq < 4; qq++)
            acc += W2[(size_t)k * C2 + h * 256 + qq * 64 + lane] *
                   attn2[h * 512 + sel * 256 + qq * 64 + lane];
        acc = wave_sum(acc);
        if (lane == 0) {
            if (sel) w_et[h * 256 + k] = acc;
            else     w_es[h * 256 + k] = acc;
        }
    }
}

// ---------------- k2: sort (layer 1) ----------------
__global__ __launch_bounds__(256) void k2_sort(const float* __restrict__ et,
        float* __restrict__ ts, int* __restrict__ perm) {
    __shared__ unsigned key[NND];
    __shared__ int pr[64];
    const int bid = blockIdx.x, t = threadIdx.x;
    sort_block(key, pr, et, ts, perm, bid >> 6, (bid & 63) * 64, t);
}

// ---------------- k3: layer-1 scan p1 (4h x 64d) + wprep1 ----------------
__global__ __launch_bounds__(256) void k3_scan1_p1(const float* __restrict__ Wx1,
        const float* __restrict__ ts1, const int* __restrict__ perm1,
        float* __restrict__ cTA, float* __restrict__ cTB,
        float* __restrict__ SA, float* __restrict__ SB) {
    __shared__ float swA[4], swB[4];
    const int bid = blockIdx.x, t = threadIdx.x;
    if (bid >= CH) { wprep_block(ts1, SA, SB, bid - CH, t, swA, swB); return; }
    const int h = t >> 6, d = t & 63;
    const int k0 = bid * CHR;
    const float tmax = ts1[h * NND + NND - 1];
    float aA = 0.f, aB = 0.f;
#pragma unroll
    for (int r = 0; r < CHR; r++) {
        float u = ts1[h * NND + k0 + r] - tmax;
        float wa = expf(u), wb = expf(LEAKY * u);
        int j = perm1[h * NND + k0 + r];
        float v = Wx1[(size_t)j * HID + h * D1 + d];
        aA += wa * v; aB += wb * v;
    }
    cTA[(h * CH + bid) * D1 + d] = aA;
    cTB[(h * CH + bid) * D1 + d] = aB;
}

// ---------------- p2: wave-parallel exclusive scan of chunk totals (in place) ------------
__global__ __launch_bounds__(256) void k_scan_p2(float* __restrict__ cTA,
        float* __restrict__ cTB, float* __restrict__ TotA, float* __restrict__ TotB,
        int logD) {
    const int t = threadIdx.x;
    const int lane = t & 63, w = t >> 6;
    const int D = 1 << logD;
    const int col = blockIdx.x * 4 + w;
    const int h = col >> logD, d = col & (D - 1);
    const size_t base = (size_t)h * CH * D + d;
    float vA[8], vB[8];
#pragma unroll
    for (int q = 0; q < 8; q++) {
        size_t o = base + (size_t)(lane * 8 + q) * D;
        vA[q] = cTA[o];
        vB[q] = cTB[o];
    }
    float laA = 0.f, laB = 0.f;
#pragma unroll
    for (int q = 0; q < 8; q++) { laA += vA[q]; laB += vB[q]; }
    float sA = laA, sB = laB;
#pragma unroll
    for (int o = 1; o < 64; o <<= 1) {
        float uA = __shfl_up(sA, o, 64);
        float uB = __shfl_up(sB, o, 64);
        if (lane >= o) { sA += uA; sB += uB; }
    }
    float totA = __shfl(sA, 63, 64);
    float totB = __shfl(sB, 63, 64);
    float runA = sA - laA, runB = sB - laB;
#pragma unroll
    for (int q = 0; q < 8; q++) {
        size_t o = base + (size_t)(lane * 8 + q) * D;
        float tA = vA[q], tB = vB[q];
        cTA[o] = runA;
        cTB[o] = runB;
        runA += tA; runB += tB;
    }
    if (lane == 0) {
        TotA[h * D + d] = totA;
        TotB[h * D + d] = totB;
    }
}

// ---------------- k5: layer-1 scan p3 ----------------
__global__ __launch_bounds__(256) void k5_scan1_p3(const float* __restrict__ Wx1,
        const float* __restrict__ ts1, const int* __restrict__ perm1,
        const float* __restrict__ cTA, const float* __restrict__ cTB,
        const float* __restrict__ TotA,
        float* __restrict__ A, float* __restrict__ B) {
    const int ch = blockIdx.x, t = threadIdx.x;
    const int h = t >> 6, d = t & 63;
    const float tmax = ts1[h * NND + NND - 1];
    float runA = cTA[(h * CH + ch) * D1 + d];
    float runB = cTB[(h * CH + ch) * D1 + d];
    const float totA = TotA[h * D1 + d];
    const int k0 = ch * CHR;
    float v[CHR], wa[CHR], wb[CHR];
#pragma unroll
    for (int r = 0; r < CHR; r++) {
        float u = ts1[h * NND + k0 + r] - tmax;
        wa[r] = expf(u); wb[r] = expf(LEAKY * u);
        int j = perm1[h * NND + k0 + r];
        v[r] = Wx1[(size_t)j * HID + h * D1 + d];
    }
#pragma unroll
    for (int r = 0; r < CHR; r++) {
        size_t o = ((size_t)(h * NP1 + k0 + r)) * D1 + d;
        A[o] = totA - runA;
        B[o] = runB;
        runA += wa[r] * v[r];
        runB += wb[r] * v[r];
    }
    if (ch == CH - 1) {
        size_t o = ((size_t)(h * NP1 + NND)) * D1 + d;
        A[o] = totA - runA;
        B[o] = runB;
    }
}

// ---------------- k6: lookup1 -> h1 bf16 k-panels + fused escore2 ----------------
__global__ __launch_bounds__(256) void k6_lookup1(const float* __restrict__ es,
        const float* __restrict__ ts,
        const float* __restrict__ A, const float* __restrict__ Bv,
        const float* __restrict__ SA, const float* __restrict__ SB,
        const float* __restrict__ w_es, const float* __restrict__ w_et,
        unsigned short* __restrict__ h1p,
        float* __restrict__ es2, float* __restrict__ et2) {
    __shared__ float hbuf[256];
    const int i = blockIdx.x, t = threadIdx.x;
    const int h = t >> 6, d = t & 63;
    const int lane = t & 63, wid = t >> 6;
    float c = es[h * NND + i];
    float tmax = ts[h * NND + NND - 1];
    float s = c + tmax;
    float m = (s >= 0.f) ? s : LEAKY * s;
    float al = expf(s - m);
    float be = expf(LEAKY * s - m);
    int k = lower_bound_f(ts + h * NND, -c);
    size_t o = ((size_t)(h * NP1 + k)) * D1 + d;
    float num = al * A[o] + be * Bv[o];
    float den = al * SA[h * NP1 + k] + be * SB[h * NP1 + k];
    float val = num / den;
    float hv = (val > 0.f) ? val : expm1f(val);
    h1p[((size_t)(t >> 3) * NND + i) * 8 + (t & 7)] = f2bf(hv);
    hbuf[t] = hv;
    __syncthreads();
    float4 hv4 = *(const float4*)&hbuf[lane * 4];
    float4 we4 = *(const float4*)&w_es[wid * HID + lane * 4];
    float4 wt4 = *(const float4*)&w_et[wid * HID + lane * 4];
    float pes = hv4.x * we4.x + hv4.y * we4.y + hv4.z * we4.z + hv4.w * we4.w;
    float pet = hv4.x * wt4.x + hv4.y * wt4.y + hv4.z * wt4.z + hv4.w * wt4.w;
    pes = wave_sum(pes);
    pet = wave_sum(pet);
    if (lane == 0) {
        es2[wid * NND + i] = pes;
        et2[wid * NND + i] = pet;
    }
}

// ---------------- k7: gemm2 plain-bf16 128x64 tile, panel staging (coalesced) | sort2 ----
__global__ __launch_bounds__(256) void k7_gemm2_sort2(
        const unsigned short* __restrict__ h1p, const unsigned short* __restrict__ W2p,
        float* __restrict__ Wx2,
        const float* __restrict__ et2, float* __restrict__ ts2, int* __restrict__ perm2) {
    union SM7 {
        struct { unsigned short Ah[512][8], Bh[256][8]; } g;
        struct { unsigned key[NND]; int pr[64]; } s;
    };
    __shared__ SM7 sm;
    const int bid = blockIdx.x, t = threadIdx.x;
    if (bid >= 512) {
        sort_block(sm.s.key, sm.s.pr, et2, ts2, perm2,
                   (bid - 512) >> 6, ((bid - 512) & 63) * 64, t);
        return;
    }
    const int lane = t & 63, w = t >> 6;
    const int n0 = (bid & 15) * 64, m0 = (bid >> 4) * 128;
    const int fr = lane & 15, kg = lane >> 4;
    f32x4 z4 = {0.f, 0.f, 0.f, 0.f};
    f32x4 acc[2][4] = {{z4, z4, z4, z4}, {z4, z4, z4, z4}};
    u16x8 rA[2], rB;
    auto load_step = [&](int k0) {
        int kgrp = (k0 >> 3) + w;     // wave w stages k-group w of this step
#pragma unroll
        for (int rr = 0; rr < 2; rr++)
            rA[rr] = *(const u16x8*)&h1p[((size_t)kgrp * NND + m0 + rr * 64 + lane) * 8];
        rB = *(const u16x8*)&W2p[((size_t)kgrp * C2 + n0 + lane) * 8];
    };
    load_step(0);
    for (int k0 = 0; k0 < HID; k0 += 32) {
#pragma unroll
        for (int rr = 0; rr < 2; rr++)
            *(u16x8*)&sm.g.Ah[w * 128 + rr * 64 + lane][0] = rA[rr];
        *(u16x8*)&sm.g.Bh[w * 64 + lane][0] = rB;
        __syncthreads();
        if (k0 + 32 < HID) load_step(k0 + 32);   // overlap with frag reads + MFMA
        bf16x8 ah[2], bh[4];
#pragma unroll
        for (int mb = 0; mb < 2; mb++)
            ah[mb] = *(bf16x8*)&sm.g.Ah[kg * 128 + w * 32 + mb * 16 + fr][0];
#pragma unroll
        for (int nb = 0; nb < 4; nb++)
            bh[nb] = *(bf16x8*)&sm.g.Bh[kg * 64 + nb * 16 + fr][0];
#pragma unroll
        for (int mb = 0; mb < 2; mb++)
#pragma unroll
            for (int nb = 0; nb < 4; nb++)
                MM(ah[mb], bh[nb], acc[mb][nb]);
        __syncthreads();
    }
#pragma unroll
    for (int mb = 0; mb < 2; mb++)
#pragma unroll
        for (int r = 0; r < 4; r++) {
            int row = m0 + w * 32 + mb * 16 + kg * 4 + r;
#pragma unroll
            for (int nb = 0; nb < 4; nb++)
                Wx2[(size_t)row * C2 + n0 + nb * 16 + fr] = acc[mb][nb][r];
        }
}

// ---------------- k8: layer-2 scan p1 + wprep2 ----------------
__global__ __launch_bounds__(256) void k8_scan2_p1(const float* __restrict__ Wx2,
        const float* __restrict__ ts2, const int* __restrict__ perm2,
        float* __restrict__ cTA, float* __restrict__ cTB,
        float* __restrict__ SA, float* __restrict__ SB) {
    __shared__ float swA[4], swB[4];
    const int bid = blockIdx.x, t = threadIdx.x;
    if (bid >= 2048) { wprep_block(ts2, SA, SB, bid - 2048, t, swA, swB); return; }
    const int ch = bid & (CH - 1), h = bid >> 9;
    const int d = t, k0 = ch * CHR;
    const float tmax = ts2[h * NND + NND - 1];
    float aA = 0.f, aB = 0.f;
#pragma unroll
    for (int r = 0; r < CHR; r++) {
        float u = ts2[h * NND + k0 + r] - tmax;
        float wa = expf(u), wb = expf(LEAKY * u);
        int j = perm2[h * NND + k0 + r];
        float v = Wx2[(size_t)j * C2 + h * D2 + d];
        aA += wa * v; aB += wb * v;
    }
    cTA[(h * CH + ch) * D2 + d] = aA;
    cTB[(h * CH + ch) * D2 + d] = aB;
}

// ---------------- k10: layer-2 scan p3 ----------------
__global__ __launch_bounds__(256) void k10_scan2_p3(const float* __restrict__ Wx2,
        const float* __restrict__ ts2, const int* __restrict__ perm2,
        const float* __restrict__ cTA, const float* __restrict__ cTB,
        const float* __restrict__ TotA,
        float* __restrict__ A, float* __restrict__ B) {
    const int bid = blockIdx.x, t = threadIdx.x;
    const int ch = bid & (CH - 1), h = bid >> 9;
    const int d = t;
    const float tmax = ts2[h * NND + NND - 1];
    float runA = cTA[(h * CH + ch) * D2 + d];
    float runB = cTB[(h * CH + ch) * D2 + d];
    const float totA = TotA[h * D2 + d];
    const int k0 = ch * CHR;
    float v[CHR], wa[CHR], wb[CHR];
#pragma unroll
    for (int r = 0; r < CHR; r++) {
        float u = ts2[h * NND + k0 + r] - tmax;
        wa[r] = expf(u); wb[r] = expf(LEAKY * u);
        int j = perm2[h * NND + k0 + r];
        v[r] = Wx2[(size_t)j * C2 + h * D2 + d];
    }
#pragma unroll
    for (int r = 0; r < CHR; r++) {
        size_t o = ((size_t)(h * NP1 + k0 + r)) * D2 + d;
        A[o] = totA - runA;
        B[o] = runB;
        runA += wa[r] * v[r];
        runB += wb[r] * v[r];
    }
    if (ch == CH - 1) {
        size_t o = ((size_t)(h * NP1 + NND)) * D2 + d;
        A[o] = totA - runA;
        B[o] = runB;
    }
}

// ---------------- k11: lookup2 (head-mean + ELU + LayerNorm) ----------------
__global__ __launch_bounds__(256) void k11_lookup2(const float* __restrict__ es,
        const float* __restrict__ ts,
        const float* __restrict__ A, const float* __restrict__ B,
        const float* __restrict__ SA, const float* __restrict__ SB,
        const float* __restrict__ gamma, const float* __restrict__ betap,
        float* __restrict__ out) {
    __shared__ float red[4];
    const int i = blockIdx.x;
    const int t = threadIdx.x;
    const int wid = t >> 6, lane = t & 63;
    float acc = 0.f;
#pragma unroll
    for (int h = 0; h < HEADS; h++) {
        float c = es[h * NND + i];
        float tmax = ts[h * NND + NND - 1];
        float s = c + tmax;
        float m = (s >= 0.f) ? s : LEAKY * s;
        float al = expf(s - m);
        float be = expf(LEAKY * s - m);
        int k = lower_bound_f(ts + h * NND, -c);
        size_t o = ((size_t)(h * NP1 + k)) * D2 + t;
        float num = al * A[o] + be * B[o];
        float den = al * SA[h * NP1 + k] + be * SB[h * NP1 + k];
        acc += num / den;
    }
    acc *= 0.25f;
    float xv = (acc > 0.f) ? acc : expm1f(acc);
    float sv = wave_sum(xv);
    if (lane == 0) red[wid] = sv;
    __syncthreads();
    float mu = (red[0] + red[1] + red[2] + red[3]) * (1.f / 256.f);
    __syncthreads();
    float dv = xv - mu;
    float s2 = wave_sum(dv * dv);
    if (lane == 0) red[wid] = s2;
    __syncthreads();
    float var = (red[0] + red[1] + red[2] + red[3]) * (1.f / 256.f);
    out[i * D2 + t] = gamma[t] * dv * rsqrtf(var + LN_EPS) + betap[t];
}

extern "C" void kernel_launch(void* const* d_in, const int* in_sizes, int n_in,
                              void* d_out, int out_size, void* d_ws, size_t ws_size,
                              hipStream_t stream) {
    const float* x     = (const float*)d_in[0];
    const float* W1    = (const float*)d_in[1];
    const float* attn1 = (const float*)d_in[2];
    const float* W2    = (const float*)d_in[3];
    const float* attn2 = (const float*)d_in[4];
    const float* gamma = (const float*)d_in[5];
    const float* betap = (const float*)d_in[6];
    float* out = (float*)d_out;

    char* ws = (char*)d_ws;
    size_t off = 0;
    auto alloc = [&](size_t nbytes) -> void* {
        void* p = (void*)(ws + off);
        off += (nbytes + 255) & ~(size_t)255;
        return p;
    };

    float* Wx1 = (float*)alloc((size_t)NND * HID * 4);
    float* Wx2 = (float*)alloc((size_t)NND * C2 * 4);
    unsigned short* h1p = (unsigned short*)alloc((size_t)NND * HID * 2);   // 32 kgrp x 4096 x 8
    float* es1 = (float*)alloc((size_t)HEADS * NND * 4);
    float* et1 = (float*)alloc((size_t)HEADS * NND * 4);
    float* es2 = (float*)alloc((size_t)HEADS * NND * 4);
    float* et2 = (float*)alloc((size_t)HEADS * NND * 4);
    float* ts1 = (float*)alloc((size_t)HEADS * NND * 4);
    float* ts2 = (float*)alloc((size_t)HEADS * NND * 4);
    int* perm1 = (int*)alloc((size_t)HEADS * NND * 4);
    int* perm2 = (int*)alloc((size_t)HEADS * NND * 4);
    float* A   = (float*)alloc((size_t)HEADS * NP1 * D2 * 4);
    float* B   = (float*)alloc((size_t)HEADS * NP1 * D2 * 4);
    float* SA  = (float*)alloc((size_t)HEADS * NP1 * 4);
    float* SB  = (float*)alloc((size_t)HEADS * NP1 * 4);
    float* cTA = (float*)alloc((size_t)HEADS * CH * D2 * 4);
    float* cTB = (float*)alloc((size_t)HEADS * CH * D2 * 4);
    float* TotA = (float*)alloc((size_t)HEADS * D2 * 4);
    float* TotB = (float*)alloc((size_t)HEADS * D2 * 4);
    unsigned short* W2p = (unsigned short*)alloc((size_t)262144 * 2);      // 32 kgrp x 1024 x 8
    float* w_es = (float*)alloc((size_t)HEADS * HID * 4);
    float* w_et = (float*)alloc((size_t)HEADS * HID * 4);
    (void)ws_size; (void)in_sizes; (void)n_in; (void)out_size;

    // ---- layer 1 ----
    k1_gemm1_prep<<<832, 256, 0, stream>>>(x, W1, attn1, W2, attn2,
                                           Wx1, es1, et1, W2p, w_es, w_et);
    k2_sort<<<256, 256, 0, stream>>>(et1, ts1, perm1);
    k3_scan1_p1<<<CH + 4, 256, 0, stream>>>(Wx1, ts1, perm1, cTA, cTB, SA, SB);
    k_scan_p2<<<64, 256, 0, stream>>>(cTA, cTB, TotA, TotB, 6);
    k5_scan1_p3<<<CH, 256, 0, stream>>>(Wx1, ts1, perm1, cTA, cTB, TotA, A, B);
    k6_lookup1<<<NND, 256, 0, stream>>>(es1, ts1, A, B, SA, SB, w_es, w_et,
                                        h1p, es2, et2);

    // ---- layer 2 ----
    k7_gemm2_sort2<<<768, 256, 0, stream>>>(h1p, W2p, Wx2, et2, ts2, perm2);
    k8_scan2_p1<<<2052, 256, 0, stream>>>(Wx2, ts2, perm2, cTA, cTB, SA, SB);
    k_scan_p2<<<256, 256, 0, stream>>>(cTA, cTB, TotA, TotB, 8);
    k10_scan2_p3<<<2048, 256, 0, stream>>>(Wx2, ts2, perm2, cTA, cTB, TotA, A, B);
    k11_lookup2<<<NND, 256, 0, stream>>>(es2, ts2, A, B, SA, SB, gamma, betap, out);
}

// Round 12
// 153.803 us; speedup vs baseline: 1.0902x; 1.0128x over previous
//
#include <hip/hip_runtime.h>
#include <math.h>

#define NND 4096
#define SDIM 128
#define HEADS 4
#define D1 64
#define HID 256
#define D2 256
#define C2 1024
#define NP1 (NND + 1)
#define CH 512
#define CHR 8
#define LEAKY 0.2f
#define LN_EPS 1e-5f

typedef __attribute__((ext_vector_type(8))) short bf16x8;
typedef __attribute__((ext_vector_type(4))) float f32x4;
typedef __attribute__((ext_vector_type(8))) unsigned short u16x8;

__device__ __forceinline__ unsigned short f2bf(float f) {
    union { float f; unsigned u; } v; v.f = f;
    unsigned r = v.u + 0x7FFFu + ((v.u >> 16) & 1u);
    return (unsigned short)(r >> 16);
}
__device__ __forceinline__ float bf2f(unsigned short s) {
    union { unsigned u; float f; } v; v.u = ((unsigned)s) << 16; return v.f;
}
__device__ __forceinline__ float wave_sum(float v) {
#pragma unroll
    for (int o = 32; o > 0; o >>= 1) v += __shfl_xor(v, o, 64);
    return v;
}
__device__ __forceinline__ int lower_bound_f(const float* __restrict__ a, float x) {
    int lo = 0, hi = NND;
    while (lo < hi) {
        int mid = (lo + hi) >> 1;
        if (a[mid] < x) lo = mid + 1; else hi = mid;
    }
    return lo;
}
// fragment-linear chunk index for gemm1: 16-row group, 8-k group
__device__ __forceinline__ int chunk_of(int row, int kg) {
    return ((row >> 4) << 6) + (kg << 4) + (row & 15);
}

#define MM(a, b, c) c = __builtin_amdgcn_mfma_f32_16x16x32_bf16(a, b, c, 0, 0, 0)

// ---------------- sort: rank of 64 elems/block vs all keys (vectorized b128 reads) -------
__device__ __forceinline__ void sort_block(unsigned* key, int* pr,
        const float* __restrict__ et,
        float* __restrict__ ts, int* __restrict__ perm, int h, int e0, int t) {
    for (int p = t; p < NND; p += 256) {
        unsigned u = __float_as_uint(et[h * NND + p]);
        key[p] = (u & 0x80000000u) ? ~u : (u | 0x80000000u);
    }
    if (t < 64) pr[t] = 0;
    __syncthreads();
    const int e = t & 63, sg = t >> 6;
    const int myIdx = e0 + e;
    const unsigned myU = key[myIdx];
    int rank = 0;
    const int kbeg = sg * (NND / 4);
    for (int kb = kbeg; kb < kbeg + NND / 4; kb += 16) {
        uint4 v0 = *(const uint4*)&key[kb];
        uint4 v1 = *(const uint4*)&key[kb + 4];
        uint4 v2 = *(const uint4*)&key[kb + 8];
        uint4 v3 = *(const uint4*)&key[kb + 12];
        unsigned vv[16] = {v0.x, v0.y, v0.z, v0.w, v1.x, v1.y, v1.z, v1.w,
                           v2.x, v2.y, v2.z, v2.w, v3.x, v3.y, v3.z, v3.w};
#pragma unroll
        for (int q = 0; q < 16; q++) {
            unsigned v = vv[q];
            rank += (int)(v < myU) + (int)((v == myU) & ((kb + q) < myIdx));
        }
    }
    atomicAdd(&pr[e], rank);
    __syncthreads();
    if (t < 64) {
        int r = pr[t];
        unsigned u = key[e0 + t];
        float f = (u & 0x80000000u) ? __uint_as_float(u ^ 0x80000000u)
                                    : __uint_as_float(~u);
        ts[h * NND + r] = f;
        perm[h * NND + r] = e0 + t;
    }
}

// ---------------- per-head scalar weight scan ----------------
__device__ __forceinline__ void wprep_block(const float* __restrict__ ts,
        float* __restrict__ SA, float* __restrict__ SB, int h, int t,
        float* swA, float* swB) {
    const int lane = t & 63, w = t >> 6;
    const float tmax = ts[h * NND + NND - 1];
    float a[16], b[16];
    float la = 0.f, lb = 0.f;
    const int kb = t * 16;
#pragma unroll
    for (int q = 0; q < 16; q++) {
        float u = ts[h * NND + kb + q] - tmax;
        a[q] = expf(u); b[q] = expf(LEAKY * u);
        la += a[q]; lb += b[q];
    }
    float sa = la, sb = lb;
#pragma unroll
    for (int o = 1; o < 64; o <<= 1) {
        float ua = __shfl_up(sa, o, 64);
        float ub = __shfl_up(sb, o, 64);
        if (lane >= o) { sa += ua; sb += ub; }
    }
    if (lane == 63) { swA[w] = sa; swB[w] = sb; }
    __syncthreads();
    float baseA = 0.f, baseB = 0.f, totA = 0.f, totB = 0.f;
#pragma unroll
    for (int ww = 0; ww < 4; ww++) {
        float va = swA[ww], vb = swB[ww];
        totA += va; totB += vb;
        if (ww < w) { baseA += va; baseB += vb; }
    }
    float preA = baseA + sa - la;
    float preB = baseB + sb - lb;
#pragma unroll
    for (int q = 0; q < 16; q++) {
        SA[h * NP1 + kb + q] = totA - preA;
        SB[h * NP1 + kb + q] = preB;
        preA += a[q]; preB += b[q];
    }
    if (t == 255) { SA[h * NP1 + NND] = 0.f; SB[h * NP1 + NND] = totB; }
}

// ---------------- k1: gemm1 (fused escore1) | W2 panel-prep | attn2 fold ------------
__global__ __launch_bounds__(256) void k1_gemm1_prep(
        const float* __restrict__ x, const float* __restrict__ W1,
        const float* __restrict__ attn1,
        const float* __restrict__ W2, const float* __restrict__ attn2,
        float* __restrict__ Wx1, float* __restrict__ es1, float* __restrict__ et1,
        unsigned short* __restrict__ W2p,
        float* __restrict__ w_es, float* __restrict__ w_et) {
    union SM1 {
        struct {
            unsigned short Ah[256][8], Al[256][8], Bh[256][8], Bl[256][8];
            float esP[2][2][32], etP[2][2][32];
        } g;
        float tile[64][65];
    };
    __shared__ SM1 sm;
    const int bid = blockIdx.x, t = threadIdx.x;
    if (bid < 256) {
        const int lane = t & 63, w = t >> 6;
        const int wm = w >> 1, wn = w & 1;
        const int h = bid & 3, n0 = h * 64, m0 = (bid >> 2) * 64;
        const int fr = lane & 15, kg = lane >> 4;
        const int arow = t >> 2, akg = t & 3;
        const int ac = chunk_of(arow, akg);
        const int brow = t & 63, bkg = t >> 6;
        const int bc = chunk_of(brow, bkg);
        f32x4 z4 = {0.f, 0.f, 0.f, 0.f};
        f32x4 acc[2][2] = {{z4, z4}, {z4, z4}};
        for (int k0 = 0; k0 < SDIM; k0 += 32) {
            {
                float fv[8];
                *(float4*)&fv[0] = *(const float4*)&x[(size_t)(m0 + arow) * SDIM + k0 + akg * 8];
                *(float4*)&fv[4] = *(const float4*)&x[(size_t)(m0 + arow) * SDIM + k0 + akg * 8 + 4];
                u16x8 ph, pl;
#pragma unroll
                for (int i = 0; i < 8; i++) {
                    unsigned short hi = f2bf(fv[i]);
                    ph[i] = hi; pl[i] = f2bf(fv[i] - bf2f(hi));
                }
                *(u16x8*)&sm.g.Ah[ac][0] = ph;
                *(u16x8*)&sm.g.Al[ac][0] = pl;
            }
            {
                u16x8 ph, pl;
#pragma unroll
                for (int i = 0; i < 8; i++) {
                    float v = W1[(size_t)(k0 + bkg * 8 + i) * HID + n0 + brow];
                    unsigned short hi = f2bf(v);
                    ph[i] = hi; pl[i] = f2bf(v - bf2f(hi));
                }
                *(u16x8*)&sm.g.Bh[bc][0] = ph;
                *(u16x8*)&sm.g.Bl[bc][0] = pl;
            }
            __syncthreads();
            bf16x8 ah0 = *(bf16x8*)&sm.g.Ah[wm * 128 + lane][0];
            bf16x8 ah1 = *(bf16x8*)&sm.g.Ah[wm * 128 + 64 + lane][0];
            bf16x8 al0 = *(bf16x8*)&sm.g.Al[wm * 128 + lane][0];
            bf16x8 al1 = *(bf16x8*)&sm.g.Al[wm * 128 + 64 + lane][0];
            bf16x8 bh0 = *(bf16x8*)&sm.g.Bh[wn * 128 + lane][0];
            bf16x8 bh1 = *(bf16x8*)&sm.g.Bh[wn * 128 + 64 + lane][0];
            bf16x8 bl0 = *(bf16x8*)&sm.g.Bl[wn * 128 + lane][0];
            bf16x8 bl1 = *(bf16x8*)&sm.g.Bl[wn * 128 + 64 + lane][0];
            MM(ah0, bh0, acc[0][0]); MM(ah0, bl0, acc[0][0]); MM(al0, bh0, acc[0][0]);
            MM(ah0, bh1, acc[0][1]); MM(ah0, bl1, acc[0][1]); MM(al0, bh1, acc[0][1]);
            MM(ah1, bh0, acc[1][0]); MM(ah1, bl0, acc[1][0]); MM(al1, bh0, acc[1][0]);
            MM(ah1, bh1, acc[1][1]); MM(ah1, bl1, acc[1][1]); MM(al1, bh1, acc[1][1]);
            __syncthreads();
        }
        const float as0 = attn1[h * 128 + wn * 32 + fr];
        const float as1 = attn1[h * 128 + wn * 32 + 16 + fr];
        const float at0 = attn1[h * 128 + 64 + wn * 32 + fr];
        const float at1 = attn1[h * 128 + 64 + wn * 32 + 16 + fr];
#pragma unroll
        for (int mb = 0; mb < 2; mb++) {
#pragma unroll
            for (int r = 0; r < 4; r++) {
                int row = m0 + wm * 32 + mb * 16 + kg * 4 + r;
#pragma unroll
                for (int nb = 0; nb < 2; nb++)
                    Wx1[(size_t)row * HID + n0 + wn * 32 + nb * 16 + fr] = acc[mb][nb][r];
                float ve = acc[mb][0][r] * as0 + acc[mb][1][r] * as1;
                float vt = acc[mb][0][r] * at0 + acc[mb][1][r] * at1;
#pragma unroll
                for (int msk = 1; msk < 16; msk <<= 1) {
                    ve += __shfl_xor(ve, msk, 64);
                    vt += __shfl_xor(vt, msk, 64);
                }
                if (fr == 0) {
                    sm.g.esP[wm][wn][mb * 16 + kg * 4 + r] = ve;
                    sm.g.etP[wm][wn][mb * 16 + kg * 4 + r] = vt;
                }
            }
        }
        __syncthreads();
        if (t < 64) {
            int wmm = t >> 5, ri = t & 31;
            es1[h * NND + m0 + t] = sm.g.esP[wmm][0][ri] + sm.g.esP[wmm][1][ri];
            et1[h * NND + m0 + t] = sm.g.etP[wmm][0][ri] + sm.g.etP[wmm][1][ri];
        }
    } else if (bid < 320) {
        const int tb = bid - 256;
        const int tk = tb & 3, tn = tb >> 2;
#pragma unroll
        for (int q = 0; q < 16; q++) {
            int idx = q * 256 + t;
            int kr = idx >> 6, nc = idx & 63;
            sm.tile[kr][nc] = W2[(size_t)(tk * 64 + kr) * C2 + tn * 64 + nc];
        }
        __syncthreads();
#pragma unroll
        for (int q = 0; q < 16; q++) {
            int idx = q * 256 + t;
            int nr = idx >> 6, kc = idx & 63;
            float v = sm.tile[kc][nr];
            int kglob = tk * 64 + kc;
            size_t o = ((size_t)(kglob >> 3) * C2 + tn * 64 + nr) * 8 + (kglob & 7);
            W2p[o] = f2bf(v);
        }
    } else {
        int g = (bid - 320) * 4 + (t >> 6);
        int lane = t & 63;
        int k = g & 255, hs = g >> 8, h = hs >> 1, sel = hs & 1;
        float acc = 0.f;
#pragma unroll
        for (int qq = 0; qq < 4; qq++)
            acc += W2[(size_t)k * C2 + h * 256 + qq * 64 + lane] *
                   attn2[h * 512 + sel * 256 + qq * 64 + lane];
        acc = wave_sum(acc);
        if (lane == 0) {
            if (sel) w_et[h * 256 + k] = acc;
            else     w_es[h * 256 + k] = acc;
        }
    }
}

// ---------------- k2: sort (layer 1) ----------------
__global__ __launch_bounds__(256) void k2_sort(const float* __restrict__ et,
        float* __restrict__ ts, int* __restrict__ perm) {
    __shared__ unsigned key[NND];
    __shared__ int pr[64];
    const int bid = blockIdx.x, t = threadIdx.x;
    sort_block(key, pr, et, ts, perm, bid >> 6, (bid & 63) * 64, t);
}

// ---------------- k3: layer-1 scan p1 (4h x 64d) + wprep1 ----------------
__global__ __launch_bounds__(256) void k3_scan1_p1(const float* __restrict__ Wx1,
        const float* __restrict__ ts1, const int* __restrict__ perm1,
        float* __restrict__ cTA, float* __restrict__ cTB,
        float* __restrict__ SA, float* __restrict__ SB) {
    __shared__ float swA[4], swB[4];
    const int bid = blockIdx.x, t = threadIdx.x;
    if (bid >= CH) { wprep_block(ts1, SA, SB, bid - CH, t, swA, swB); return; }
    const int h = t >> 6, d = t & 63;
    const int k0 = bid * CHR;
    const float tmax = ts1[h * NND + NND - 1];
    float aA = 0.f, aB = 0.f;
#pragma unroll
    for (int r = 0; r < CHR; r++) {
        float u = ts1[h * NND + k0 + r] - tmax;
        float wa = expf(u), wb = expf(LEAKY * u);
        int j = perm1[h * NND + k0 + r];
        float v = Wx1[(size_t)j * HID + h * D1 + d];
        aA += wa * v; aB += wb * v;
    }
    cTA[(h * CH + bid) * D1 + d] = aA;
    cTB[(h * CH + bid) * D1 + d] = aB;
}

// ---------------- p2: wave-parallel exclusive scan of chunk totals (in place) ------------
__global__ __launch_bounds__(256) void k_scan_p2(float* __restrict__ cTA,
        float* __restrict__ cTB, float* __restrict__ TotA, float* __restrict__ TotB,
        int logD) {
    const int t = threadIdx.x;
    const int lane = t & 63, w = t >> 6;
    const int D = 1 << logD;
    const int col = blockIdx.x * 4 + w;
    const int h = col >> logD, d = col & (D - 1);
    const size_t base = (size_t)h * CH * D + d;
    float vA[8], vB[8];
#pragma unroll
    for (int q = 0; q < 8; q++) {
        size_t o = base + (size_t)(lane * 8 + q) * D;
        vA[q] = cTA[o];
        vB[q] = cTB[o];
    }
    float laA = 0.f, laB = 0.f;
#pragma unroll
    for (int q = 0; q < 8; q++) { laA += vA[q]; laB += vB[q]; }
    float sA = laA, sB = laB;
#pragma unroll
    for (int o = 1; o < 64; o <<= 1) {
        float uA = __shfl_up(sA, o, 64);
        float uB = __shfl_up(sB, o, 64);
        if (lane >= o) { sA += uA; sB += uB; }
    }
    float totA = __shfl(sA, 63, 64);
    float totB = __shfl(sB, 63, 64);
    float runA = sA - laA, runB = sB - laB;
#pragma unroll
    for (int q = 0; q < 8; q++) {
        size_t o = base + (size_t)(lane * 8 + q) * D;
        float tA = vA[q], tB = vB[q];
        cTA[o] = runA;
        cTB[o] = runB;
        runA += tA; runB += tB;
    }
    if (lane == 0) {
        TotA[h * D + d] = totA;
        TotB[h * D + d] = totB;
    }
}

// ---------------- k5: layer-1 scan p3 (fp32 A/B) ----------------
__global__ __launch_bounds__(256) void k5_scan1_p3(const float* __restrict__ Wx1,
        const float* __restrict__ ts1, const int* __restrict__ perm1,
        const float* __restrict__ cTA, const float* __restrict__ cTB,
        const float* __restrict__ TotA,
        float* __restrict__ A, float* __restrict__ B) {
    const int ch = blockIdx.x, t = threadIdx.x;
    const int h = t >> 6, d = t & 63;
    const float tmax = ts1[h * NND + NND - 1];
    float runA = cTA[(h * CH + ch) * D1 + d];
    float runB = cTB[(h * CH + ch) * D1 + d];
    const float totA = TotA[h * D1 + d];
    const int k0 = ch * CHR;
    float v[CHR], wa[CHR], wb[CHR];
#pragma unroll
    for (int r = 0; r < CHR; r++) {
        float u = ts1[h * NND + k0 + r] - tmax;
        wa[r] = expf(u); wb[r] = expf(LEAKY * u);
        int j = perm1[h * NND + k0 + r];
        v[r] = Wx1[(size_t)j * HID + h * D1 + d];
    }
#pragma unroll
    for (int r = 0; r < CHR; r++) {
        size_t o = ((size_t)(h * NP1 + k0 + r)) * D1 + d;
        A[o] = totA - runA;
        B[o] = runB;
        runA += wa[r] * v[r];
        runB += wb[r] * v[r];
    }
    if (ch == CH - 1) {
        size_t o = ((size_t)(h * NP1 + NND)) * D1 + d;
        A[o] = totA - runA;
        B[o] = runB;
    }
}

// ---------------- k6: lookup1 -> h1 bf16 k-panels + fused escore2 ----------------
__global__ __launch_bounds__(256) void k6_lookup1(const float* __restrict__ es,
        const float* __restrict__ ts,
        const float* __restrict__ A, const float* __restrict__ Bv,
        const float* __restrict__ SA, const float* __restrict__ SB,
        const float* __restrict__ w_es, const float* __restrict__ w_et,
        unsigned short* __restrict__ h1p,
        float* __restrict__ es2, float* __restrict__ et2) {
    __shared__ float hbuf[256];
    const int i = blockIdx.x, t = threadIdx.x;
    const int h = t >> 6, d = t & 63;
    const int lane = t & 63, wid = t >> 6;
    float c = es[h * NND + i];
    float tmax = ts[h * NND + NND - 1];
    float s = c + tmax;
    float m = (s >= 0.f) ? s : LEAKY * s;
    float al = expf(s - m);
    float be = expf(LEAKY * s - m);
    int k = lower_bound_f(ts + h * NND, -c);
    size_t o = ((size_t)(h * NP1 + k)) * D1 + d;
    float num = al * A[o] + be * Bv[o];
    float den = al * SA[h * NP1 + k] + be * SB[h * NP1 + k];
    float val = num / den;
    float hv = (val > 0.f) ? val : expm1f(val);
    h1p[((size_t)(t >> 3) * NND + i) * 8 + (t & 7)] = f2bf(hv);
    hbuf[t] = hv;
    __syncthreads();
    float4 hv4 = *(const float4*)&hbuf[lane * 4];
    float4 we4 = *(const float4*)&w_es[wid * HID + lane * 4];
    float4 wt4 = *(const float4*)&w_et[wid * HID + lane * 4];
    float pes = hv4.x * we4.x + hv4.y * we4.y + hv4.z * we4.z + hv4.w * we4.w;
    float pet = hv4.x * wt4.x + hv4.y * wt4.y + hv4.z * wt4.z + hv4.w * wt4.w;
    pes = wave_sum(pes);
    pet = wave_sum(pet);
    if (lane == 0) {
        es2[wid * NND + i] = pes;
        et2[wid * NND + i] = pet;
    }
}

// ---------------- k7: gemm2 plain-bf16 128x64 tile, panel staging | sort2 ----------------
__global__ __launch_bounds__(256) void k7_gemm2_sort2(
        const unsigned short* __restrict__ h1p, const unsigned short* __restrict__ W2p,
        float* __restrict__ Wx2,
        const float* __restrict__ et2, float* __restrict__ ts2, int* __restrict__ perm2) {
    union SM7 {
        struct { unsigned short Ah[512][8], Bh[256][8]; } g;
        struct { unsigned key[NND]; int pr[64]; } s;
    };
    __shared__ SM7 sm;
    const int bid = blockIdx.x, t = threadIdx.x;
    if (bid >= 512) {
        sort_block(sm.s.key, sm.s.pr, et2, ts2, perm2,
                   (bid - 512) >> 6, ((bid - 512) & 63) * 64, t);
        return;
    }
    const int lane = t & 63, w = t >> 6;
    const int n0 = (bid & 15) * 64, m0 = (bid >> 4) * 128;
    const int fr = lane & 15, kg = lane >> 4;
    f32x4 z4 = {0.f, 0.f, 0.f, 0.f};
    f32x4 acc[2][4] = {{z4, z4, z4, z4}, {z4, z4, z4, z4}};
    u16x8 rA[2], rB;
    auto load_step = [&](int k0) {
        int kgrp = (k0 >> 3) + w;
#pragma unroll
        for (int rr = 0; rr < 2; rr++)
            rA[rr] = *(const u16x8*)&h1p[((size_t)kgrp * NND + m0 + rr * 64 + lane) * 8];
        rB = *(const u16x8*)&W2p[((size_t)kgrp * C2 + n0 + lane) * 8];
    };
    load_step(0);
    for (int k0 = 0; k0 < HID; k0 += 32) {
#pragma unroll
        for (int rr = 0; rr < 2; rr++)
            *(u16x8*)&sm.g.Ah[w * 128 + rr * 64 + lane][0] = rA[rr];
        *(u16x8*)&sm.g.Bh[w * 64 + lane][0] = rB;
        __syncthreads();
        if (k0 + 32 < HID) load_step(k0 + 32);
        bf16x8 ah[2], bh[4];
#pragma unroll
        for (int mb = 0; mb < 2; mb++)
            ah[mb] = *(bf16x8*)&sm.g.Ah[kg * 128 + w * 32 + mb * 16 + fr][0];
#pragma unroll
        for (int nb = 0; nb < 4; nb++)
            bh[nb] = *(bf16x8*)&sm.g.Bh[kg * 64 + nb * 16 + fr][0];
#pragma unroll
        for (int mb = 0; mb < 2; mb++)
#pragma unroll
            for (int nb = 0; nb < 4; nb++)
                MM(ah[mb], bh[nb], acc[mb][nb]);
        __syncthreads();
    }
#pragma unroll
    for (int mb = 0; mb < 2; mb++)
#pragma unroll
        for (int r = 0; r < 4; r++) {
            int row = m0 + w * 32 + mb * 16 + kg * 4 + r;
#pragma unroll
            for (int nb = 0; nb < 4; nb++)
                Wx2[(size_t)row * C2 + n0 + nb * 16 + fr] = acc[mb][nb][r];
        }
}

// ---------------- k8: layer-2 scan p1 + wprep2 ----------------
__global__ __launch_bounds__(256) void k8_scan2_p1(const float* __restrict__ Wx2,
        const float* __restrict__ ts2, const int* __restrict__ perm2,
        float* __restrict__ cTA, float* __restrict__ cTB,
        float* __restrict__ SA, float* __restrict__ SB) {
    __shared__ float swA[4], swB[4];
    const int bid = blockIdx.x, t = threadIdx.x;
    if (bid >= 2048) { wprep_block(ts2, SA, SB, bid - 2048, t, swA, swB); return; }
    const int ch = bid & (CH - 1), h = bid >> 9;
    const int d = t, k0 = ch * CHR;
    const float tmax = ts2[h * NND + NND - 1];
    float aA = 0.f, aB = 0.f;
#pragma unroll
    for (int r = 0; r < CHR; r++) {
        float u = ts2[h * NND + k0 + r] - tmax;
        float wa = expf(u), wb = expf(LEAKY * u);
        int j = perm2[h * NND + k0 + r];
        float v = Wx2[(size_t)j * C2 + h * D2 + d];
        aA += wa * v; aB += wb * v;
    }
    cTA[(h * CH + ch) * D2 + d] = aA;
    cTB[(h * CH + ch) * D2 + d] = aB;
}

// ---------------- k10: layer-2 scan p3 -> packed bf16 (A | B<<16) ----------------
__global__ __launch_bounds__(256) void k10_scan2_p3(const float* __restrict__ Wx2,
        const float* __restrict__ ts2, const int* __restrict__ perm2,
        const float* __restrict__ cTA, const float* __restrict__ cTB,
        const float* __restrict__ TotA,
        unsigned* __restrict__ AB) {
    const int bid = blockIdx.x, t = threadIdx.x;
    const int ch = bid & (CH - 1), h = bid >> 9;
    const int d = t;
    const float tmax = ts2[h * NND + NND - 1];
    float runA = cTA[(h * CH + ch) * D2 + d];
    float runB = cTB[(h * CH + ch) * D2 + d];
    const float totA = TotA[h * D2 + d];
    const int k0 = ch * CHR;
    float v[CHR], wa[CHR], wb[CHR];
#pragma unroll
    for (int r = 0; r < CHR; r++) {
        float u = ts2[h * NND + k0 + r] - tmax;
        wa[r] = expf(u); wb[r] = expf(LEAKY * u);
        int j = perm2[h * NND + k0 + r];
        v[r] = Wx2[(size_t)j * C2 + h * D2 + d];
    }
#pragma unroll
    for (int r = 0; r < CHR; r++) {
        size_t o = ((size_t)(h * NP1 + k0 + r)) * D2 + d;
        AB[o] = (unsigned)f2bf(totA - runA) | ((unsigned)f2bf(runB) << 16);
        runA += wa[r] * v[r];
        runB += wb[r] * v[r];
    }
    if (ch == CH - 1) {
        size_t o = ((size_t)(h * NP1 + NND)) * D2 + d;
        AB[o] = (unsigned)f2bf(totA - runA) | ((unsigned)f2bf(runB) << 16);
    }
}

// ---------------- k11: lookup2 (packed A/B; head-mean + ELU + LayerNorm) ----------------
__global__ __launch_bounds__(256) void k11_lookup2(const float* __restrict__ es,
        const float* __restrict__ ts,
        const unsigned* __restrict__ AB,
        const float* __restrict__ SA, const float* __restrict__ SB,
        const float* __restrict__ gamma, const float* __restrict__ betap,
        float* __restrict__ out) {
    __shared__ float red[4];
    const int i = blockIdx.x;
    const int t = threadIdx.x;
    const int wid = t >> 6, lane = t & 63;
    float acc = 0.f;
#pragma unroll
    for (int h = 0; h < HEADS; h++) {
        float c = es[h * NND + i];
        float tmax = ts[h * NND + NND - 1];
        float s = c + tmax;
        float m = (s >= 0.f) ? s : LEAKY * s;
        float al = expf(s - m);
        float be = expf(LEAKY * s - m);
        int k = lower_bound_f(ts + h * NND, -c);
        size_t o = ((size_t)(h * NP1 + k)) * D2 + t;
        unsigned u = AB[o];
        float Av = bf2f((unsigned short)(u & 0xFFFFu));
        float Bu = bf2f((unsigned short)(u >> 16));
        float num = al * Av + be * Bu;
        float den = al * SA[h * NP1 + k] + be * SB[h * NP1 + k];
        acc += num / den;
    }
    acc *= 0.25f;
    float xv = (acc > 0.f) ? acc : expm1f(acc);
    float sv = wave_sum(xv);
    if (lane == 0) red[wid] = sv;
    __syncthreads();
    float mu = (red[0] + red[1] + red[2] + red[3]) * (1.f / 256.f);
    __syncthreads();
    float dv = xv - mu;
    float s2 = wave_sum(dv * dv);
    if (lane == 0) red[wid] = s2;
    __syncthreads();
    float var = (red[0] + red[1] + red[2] + red[3]) * (1.f / 256.f);
    out[i * D2 + t] = gamma[t] * dv * rsqrtf(var + LN_EPS) + betap[t];
}

extern "C" void kernel_launch(void* const* d_in, const int* in_sizes, int n_in,
                              void* d_out, int out_size, void* d_ws, size_t ws_size,
                              hipStream_t stream) {
    const float* x     = (const float*)d_in[0];
    const float* W1    = (const float*)d_in[1];
    const float* attn1 = (const float*)d_in[2];
    const float* W2    = (const float*)d_in[3];
    const float* attn2 = (const float*)d_in[4];
    const float* gamma = (const float*)d_in[5];
    const float* betap = (const float*)d_in[6];
    float* out = (float*)d_out;

    char* ws = (char*)d_ws;
    size_t off = 0;
    auto alloc = [&](size_t nbytes) -> void* {
        void* p = (void*)(ws + off);
        off += (nbytes + 255) & ~(size_t)255;
        return p;
    };

    float* Wx1 = (float*)alloc((size_t)NND * HID * 4);
    float* Wx2 = (float*)alloc((size_t)NND * C2 * 4);
    unsigned short* h1p = (unsigned short*)alloc((size_t)NND * HID * 2);
    float* es1 = (float*)alloc((size_t)HEADS * NND * 4);
    float* et1 = (float*)alloc((size_t)HEADS * NND * 4);
    float* es2 = (float*)alloc((size_t)HEADS * NND * 4);
    float* et2 = (float*)alloc((size_t)HEADS * NND * 4);
    float* ts1 = (float*)alloc((size_t)HEADS * NND * 4);
    float* ts2 = (float*)alloc((size_t)HEADS * NND * 4);
    int* perm1 = (int*)alloc((size_t)HEADS * NND * 4);
    int* perm2 = (int*)alloc((size_t)HEADS * NND * 4);
    float* A   = (float*)alloc((size_t)HEADS * NP1 * D1 * 4);   // layer-1 only (fp32)
    float* B   = (float*)alloc((size_t)HEADS * NP1 * D1 * 4);
    unsigned* AB2 = (unsigned*)alloc((size_t)HEADS * NP1 * D2 * 4);  // layer-2 packed bf16 pair
    float* SA  = (float*)alloc((size_t)HEADS * NP1 * 4);
    float* SB  = (float*)alloc((size_t)HEADS * NP1 * 4);
    float* cTA = (float*)alloc((size_t)HEADS * CH * D2 * 4);
    float* cTB = (float*)alloc((size_t)HEADS * CH * D2 * 4);
    float* TotA = (float*)alloc((size_t)HEADS * D2 * 4);
    float* TotB = (float*)alloc((size_t)HEADS * D2 * 4);
    unsigned short* W2p = (unsigned short*)alloc((size_t)262144 * 2);
    float* w_es = (float*)alloc((size_t)HEADS * HID * 4);
    float* w_et = (float*)alloc((size_t)HEADS * HID * 4);
    (void)ws_size; (void)in_sizes; (void)n_in; (void)out_size;

    // ---- layer 1 ----
    k1_gemm1_prep<<<832, 256, 0, stream>>>(x, W1, attn1, W2, attn2,
                                           Wx1, es1, et1, W2p, w_es, w_et);
    k2_sort<<<256, 256, 0, stream>>>(et1, ts1, perm1);
    k3_scan1_p1<<<CH + 4, 256, 0, stream>>>(Wx1, ts1, perm1, cTA, cTB, SA, SB);
    k_scan_p2<<<64, 256, 0, stream>>>(cTA, cTB, TotA, TotB, 6);
    k5_scan1_p3<<<CH, 256, 0, stream>>>(Wx1, ts1, perm1, cTA, cTB, TotA, A, B);
    k6_lookup1<<<NND, 256, 0, stream>>>(es1, ts1, A, B, SA, SB, w_es, w_et,
                                        h1p, es2, et2);

    // ---- layer 2 ----
    k7_gemm2_sort2<<<768, 256, 0, stream>>>(h1p, W2p, Wx2, et2, ts2, perm2);
    k8_scan2_p1<<<2052, 256, 0, stream>>>(Wx2, ts2, perm2, cTA, cTB, SA, SB);
    k_scan_p2<<<256, 256, 0, stream>>>(cTA, cTB, TotA, TotB, 8);
    k10_scan2_p3<<<2048, 256, 0, stream>>>(Wx2, ts2, perm2, cTA, cTB, TotA, AB2);
    k11_lookup2<<<NND, 256, 0, stream>>>(es2, ts2, AB2, SA, SB, gamma, betap, out);
}

// Round 14
// 148.993 us; speedup vs baseline: 1.1254x; 1.0323x over previous
//
#include <hip/hip_runtime.h>
#include <math.h>

#define NND 4096
#define SDIM 128
#define HEADS 4
#define D1 64
#define HID 256
#define D2 256
#define C2 1024
#define NP1 (NND + 1)
#define CH 512
#define CHR 8
#define LEAKY 0.2f
#define LN_EPS 1e-5f

typedef __attribute__((ext_vector_type(8))) short bf16x8;
typedef __attribute__((ext_vector_type(4))) float f32x4;
typedef __attribute__((ext_vector_type(8))) unsigned short u16x8;

__device__ __forceinline__ unsigned short f2bf(float f) {
    union { float f; unsigned u; } v; v.f = f;
    unsigned r = v.u + 0x7FFFu + ((v.u >> 16) & 1u);
    return (unsigned short)(r >> 16);
}
__device__ __forceinline__ float bf2f(unsigned short s) {
    union { unsigned u; float f; } v; v.u = ((unsigned)s) << 16; return v.f;
}
__device__ __forceinline__ float wave_sum(float v) {
#pragma unroll
    for (int o = 32; o > 0; o >>= 1) v += __shfl_xor(v, o, 64);
    return v;
}
__device__ __forceinline__ int lower_bound_f(const float* __restrict__ a, float x) {
    int lo = 0, hi = NND;
    while (lo < hi) {
        int mid = (lo + hi) >> 1;
        if (a[mid] < x) lo = mid + 1; else hi = mid;
    }
    return lo;
}
// fragment-linear chunk index for gemm1: 16-row group, 8-k group
__device__ __forceinline__ int chunk_of(int row, int kg) {
    return ((row >> 4) << 6) + (kg << 4) + (row & 15);
}

#define MM(a, b, c) c = __builtin_amdgcn_mfma_f32_16x16x32_bf16(a, b, c, 0, 0, 0)

// ---------------- sort: rank of 64 elems/block vs all keys (vectorized b128 reads) -------
__device__ __forceinline__ void sort_block(unsigned* key, int* pr,
        const float* __restrict__ et,
        float* __restrict__ ts, int* __restrict__ perm, int h, int e0, int t) {
    for (int p = t; p < NND; p += 256) {
        unsigned u = __float_as_uint(et[h * NND + p]);
        key[p] = (u & 0x80000000u) ? ~u : (u | 0x80000000u);
    }
    if (t < 64) pr[t] = 0;
    __syncthreads();
    const int e = t & 63, sg = t >> 6;
    const int myIdx = e0 + e;
    const unsigned myU = key[myIdx];
    int rank = 0;
    const int kbeg = sg * (NND / 4);
    for (int kb = kbeg; kb < kbeg + NND / 4; kb += 16) {
        uint4 v0 = *(const uint4*)&key[kb];
        uint4 v1 = *(const uint4*)&key[kb + 4];
        uint4 v2 = *(const uint4*)&key[kb + 8];
        uint4 v3 = *(const uint4*)&key[kb + 12];
        unsigned vv[16] = {v0.x, v0.y, v0.z, v0.w, v1.x, v1.y, v1.z, v1.w,
                           v2.x, v2.y, v2.z, v2.w, v3.x, v3.y, v3.z, v3.w};
#pragma unroll
        for (int q = 0; q < 16; q++) {
            unsigned v = vv[q];
            rank += (int)(v < myU) + (int)((v == myU) & ((kb + q) < myIdx));
        }
    }
    atomicAdd(&pr[e], rank);
    __syncthreads();
    if (t < 64) {
        int r = pr[t];
        unsigned u = key[e0 + t];
        float f = (u & 0x80000000u) ? __uint_as_float(u ^ 0x80000000u)
                                    : __uint_as_float(~u);
        ts[h * NND + r] = f;
        perm[h * NND + r] = e0 + t;
    }
}

// ---------------- per-head scalar weight scan ----------------
__device__ __forceinline__ void wprep_block(const float* __restrict__ ts,
        float* __restrict__ SA, float* __restrict__ SB, int h, int t,
        float* swA, float* swB) {
    const int lane = t & 63, w = t >> 6;
    const float tmax = ts[h * NND + NND - 1];
    float a[16], b[16];
    float la = 0.f, lb = 0.f;
    const int kb = t * 16;
#pragma unroll
    for (int q = 0; q < 16; q++) {
        float u = ts[h * NND + kb + q] - tmax;
        a[q] = __expf(u); b[q] = __expf(LEAKY * u);
        la += a[q]; lb += b[q];
    }
    float sa = la, sb = lb;
#pragma unroll
    for (int o = 1; o < 64; o <<= 1) {
        float ua = __shfl_up(sa, o, 64);
        float ub = __shfl_up(sb, o, 64);
        if (lane >= o) { sa += ua; sb += ub; }
    }
    if (lane == 63) { swA[w] = sa; swB[w] = sb; }
    __syncthreads();
    float baseA = 0.f, baseB = 0.f, totA = 0.f, totB = 0.f;
#pragma unroll
    for (int ww = 0; ww < 4; ww++) {
        float va = swA[ww], vb = swB[ww];
        totA += va; totB += vb;
        if (ww < w) { baseA += va; baseB += vb; }
    }
    float preA = baseA + sa - la;
    float preB = baseB + sb - lb;
#pragma unroll
    for (int q = 0; q < 16; q++) {
        SA[h * NP1 + kb + q] = totA - preA;
        SB[h * NP1 + kb + q] = preB;
        preA += a[q]; preB += b[q];
    }
    if (t == 255) { SA[h * NP1 + NND] = 0.f; SB[h * NP1 + NND] = totB; }
}

// ---------------- k1: gemm1 (fused escore1) | W2 panel-prep | attn2 fold ------------
__global__ __launch_bounds__(256) void k1_gemm1_prep(
        const float* __restrict__ x, const float* __restrict__ W1,
        const float* __restrict__ attn1,
        const float* __restrict__ W2, const float* __restrict__ attn2,
        float* __restrict__ Wx1, float* __restrict__ es1, float* __restrict__ et1,
        unsigned short* __restrict__ W2p,
        float* __restrict__ w_es, float* __restrict__ w_et) {
    union SM1 {
        struct {
            unsigned short Ah[256][8], Al[256][8], Bh[256][8], Bl[256][8];
            float esP[2][2][32], etP[2][2][32];
        } g;
        float tile[64][65];
    };
    __shared__ SM1 sm;
    const int bid = blockIdx.x, t = threadIdx.x;
    if (bid < 256) {
        const int lane = t & 63, w = t >> 6;
        const int wm = w >> 1, wn = w & 1;
        const int h = bid & 3, n0 = h * 64, m0 = (bid >> 2) * 64;
        const int fr = lane & 15, kg = lane >> 4;
        const int arow = t >> 2, akg = t & 3;
        const int ac = chunk_of(arow, akg);
        const int brow = t & 63, bkg = t >> 6;
        const int bc = chunk_of(brow, bkg);
        f32x4 z4 = {0.f, 0.f, 0.f, 0.f};
        f32x4 acc[2][2] = {{z4, z4}, {z4, z4}};
        for (int k0 = 0; k0 < SDIM; k0 += 32) {
            {
                float fv[8];
                *(float4*)&fv[0] = *(const float4*)&x[(size_t)(m0 + arow) * SDIM + k0 + akg * 8];
                *(float4*)&fv[4] = *(const float4*)&x[(size_t)(m0 + arow) * SDIM + k0 + akg * 8 + 4];
                u16x8 ph, pl;
#pragma unroll
                for (int i = 0; i < 8; i++) {
                    unsigned short hi = f2bf(fv[i]);
                    ph[i] = hi; pl[i] = f2bf(fv[i] - bf2f(hi));
                }
                *(u16x8*)&sm.g.Ah[ac][0] = ph;
                *(u16x8*)&sm.g.Al[ac][0] = pl;
            }
            {
                u16x8 ph, pl;
#pragma unroll
                for (int i = 0; i < 8; i++) {
                    float v = W1[(size_t)(k0 + bkg * 8 + i) * HID + n0 + brow];
                    unsigned short hi = f2bf(v);
                    ph[i] = hi; pl[i] = f2bf(v - bf2f(hi));
                }
                *(u16x8*)&sm.g.Bh[bc][0] = ph;
                *(u16x8*)&sm.g.Bl[bc][0] = pl;
            }
            __syncthreads();
            bf16x8 ah0 = *(bf16x8*)&sm.g.Ah[wm * 128 + lane][0];
            bf16x8 ah1 = *(bf16x8*)&sm.g.Ah[wm * 128 + 64 + lane][0];
            bf16x8 al0 = *(bf16x8*)&sm.g.Al[wm * 128 + lane][0];
            bf16x8 al1 = *(bf16x8*)&sm.g.Al[wm * 128 + 64 + lane][0];
            bf16x8 bh0 = *(bf16x8*)&sm.g.Bh[wn * 128 + lane][0];
            bf16x8 bh1 = *(bf16x8*)&sm.g.Bh[wn * 128 + 64 + lane][0];
            bf16x8 bl0 = *(bf16x8*)&sm.g.Bl[wn * 128 + lane][0];
            bf16x8 bl1 = *(bf16x8*)&sm.g.Bl[wn * 128 + 64 + lane][0];
            MM(ah0, bh0, acc[0][0]); MM(ah0, bl0, acc[0][0]); MM(al0, bh0, acc[0][0]);
            MM(ah0, bh1, acc[0][1]); MM(ah0, bl1, acc[0][1]); MM(al0, bh1, acc[0][1]);
            MM(ah1, bh0, acc[1][0]); MM(ah1, bl0, acc[1][0]); MM(al1, bh0, acc[1][0]);
            MM(ah1, bh1, acc[1][1]); MM(ah1, bl1, acc[1][1]); MM(al1, bh1, acc[1][1]);
            __syncthreads();
        }
        const float as0 = attn1[h * 128 + wn * 32 + fr];
        const float as1 = attn1[h * 128 + wn * 32 + 16 + fr];
        const float at0 = attn1[h * 128 + 64 + wn * 32 + fr];
        const float at1 = attn1[h * 128 + 64 + wn * 32 + 16 + fr];
#pragma unroll
        for (int mb = 0; mb < 2; mb++) {
#pragma unroll
            for (int r = 0; r < 4; r++) {
                int row = m0 + wm * 32 + mb * 16 + kg * 4 + r;
#pragma unroll
                for (int nb = 0; nb < 2; nb++)
                    Wx1[(size_t)row * HID + n0 + wn * 32 + nb * 16 + fr] = acc[mb][nb][r];
                float ve = acc[mb][0][r] * as0 + acc[mb][1][r] * as1;
                float vt = acc[mb][0][r] * at0 + acc[mb][1][r] * at1;
#pragma unroll
                for (int msk = 1; msk < 16; msk <<= 1) {
                    ve += __shfl_xor(ve, msk, 64);
                    vt += __shfl_xor(vt, msk, 64);
                }
                if (fr == 0) {
                    sm.g.esP[wm][wn][mb * 16 + kg * 4 + r] = ve;
                    sm.g.etP[wm][wn][mb * 16 + kg * 4 + r] = vt;
                }
            }
        }
        __syncthreads();
        if (t < 64) {
            int wmm = t >> 5, ri = t & 31;
            es1[h * NND + m0 + t] = sm.g.esP[wmm][0][ri] + sm.g.esP[wmm][1][ri];
            et1[h * NND + m0 + t] = sm.g.etP[wmm][0][ri] + sm.g.etP[wmm][1][ri];
        }
    } else if (bid < 320) {
        const int tb = bid - 256;
        const int tk = tb & 3, tn = tb >> 2;
#pragma unroll
        for (int q = 0; q < 16; q++) {
            int idx = q * 256 + t;
            int kr = idx >> 6, nc = idx & 63;
            sm.tile[kr][nc] = W2[(size_t)(tk * 64 + kr) * C2 + tn * 64 + nc];
        }
        __syncthreads();
#pragma unroll
        for (int q = 0; q < 16; q++) {
            int idx = q * 256 + t;
            int nr = idx >> 6, kc = idx & 63;
            float v = sm.tile[kc][nr];
            int kglob = tk * 64 + kc;
            size_t o = ((size_t)(kglob >> 3) * C2 + tn * 64 + nr) * 8 + (kglob & 7);
            W2p[o] = f2bf(v);
        }
    } else {
        int g = (bid - 320) * 4 + (t >> 6);
        int lane = t & 63;
        int k = g & 255, hs = g >> 8, h = hs >> 1, sel = hs & 1;
        float acc = 0.f;
#pragma unroll
        for (int qq = 0; qq < 4; qq++)
            acc += W2[(size_t)k * C2 + h * 256 + qq * 64 + lane] *
                   attn2[h * 512 + sel * 256 + qq * 64 + lane];
        acc = wave_sum(acc);
        if (lane == 0) {
            if (sel) w_et[h * 256 + k] = acc;
            else     w_es[h * 256 + k] = acc;
        }
    }
}

// ---------------- k2: sort (layer 1) ----------------
__global__ __launch_bounds__(256) void k2_sort(const float* __restrict__ et,
        float* __restrict__ ts, int* __restrict__ perm) {
    __shared__ unsigned key[NND];
    __shared__ int pr[64];
    const int bid = blockIdx.x, t = threadIdx.x;
    sort_block(key, pr, et, ts, perm, bid >> 6, (bid & 63) * 64, t);
}

// ---------------- k3: layer-1 scan p1 (4h x 64d) + wprep1 ----------------
__global__ __launch_bounds__(256) void k3_scan1_p1(const float* __restrict__ Wx1,
        const float* __restrict__ ts1, const int* __restrict__ perm1,
        float* __restrict__ cTA, float* __restrict__ cTB,
        float* __restrict__ SA, float* __restrict__ SB) {
    __shared__ float swA[4], swB[4];
    const int bid = blockIdx.x, t = threadIdx.x;
    if (bid >= CH) { wprep_block(ts1, SA, SB, bid - CH, t, swA, swB); return; }
    const int h = t >> 6, d = t & 63;
    const int k0 = bid * CHR;
    const float tmax = ts1[h * NND + NND - 1];
    float aA = 0.f, aB = 0.f;
#pragma unroll
    for (int r = 0; r < CHR; r++) {
        float u = ts1[h * NND + k0 + r] - tmax;
        float wa = __expf(u), wb = __expf(LEAKY * u);
        int j = perm1[h * NND + k0 + r];
        float v = Wx1[(size_t)j * HID + h * D1 + d];
        aA += wa * v; aB += wb * v;
    }
    cTA[(h * CH + bid) * D1 + d] = aA;
    cTB[(h * CH + bid) * D1 + d] = aB;
}

// ---------------- p2: wave-parallel exclusive scan of chunk totals (in place) ------------
__global__ __launch_bounds__(256) void k_scan_p2(float* __restrict__ cTA,
        float* __restrict__ cTB, float* __restrict__ TotA, float* __restrict__ TotB,
        int logD) {
    const int t = threadIdx.x;
    const int lane = t & 63, w = t >> 6;
    const int D = 1 << logD;
    const int col = blockIdx.x * 4 + w;
    const int h = col >> logD, d = col & (D - 1);
    const size_t base = (size_t)h * CH * D + d;
    float vA[8], vB[8];
#pragma unroll
    for (int q = 0; q < 8; q++) {
        size_t o = base + (size_t)(lane * 8 + q) * D;
        vA[q] = cTA[o];
        vB[q] = cTB[o];
    }
    float laA = 0.f, laB = 0.f;
#pragma unroll
    for (int q = 0; q < 8; q++) { laA += vA[q]; laB += vB[q]; }
    float sA = laA, sB = laB;
#pragma unroll
    for (int o = 1; o < 64; o <<= 1) {
        float uA = __shfl_up(sA, o, 64);
        float uB = __shfl_up(sB, o, 64);
        if (lane >= o) { sA += uA; sB += uB; }
    }
    float totA = __shfl(sA, 63, 64);
    float totB = __shfl(sB, 63, 64);
    float runA = sA - laA, runB = sB - laB;
#pragma unroll
    for (int q = 0; q < 8; q++) {
        size_t o = base + (size_t)(lane * 8 + q) * D;
        float tA = vA[q], tB = vB[q];
        cTA[o] = runA;
        cTB[o] = runB;
        runA += tA; runB += tB;
    }
    if (lane == 0) {
        TotA[h * D + d] = totA;
        TotB[h * D + d] = totB;
    }
}

// ---------------- k5: layer-1 scan p3 (fp32 A/B) ----------------
__global__ __launch_bounds__(256) void k5_scan1_p3(const float* __restrict__ Wx1,
        const float* __restrict__ ts1, const int* __restrict__ perm1,
        const float* __restrict__ cTA, const float* __restrict__ cTB,
        const float* __restrict__ TotA,
        float* __restrict__ A, float* __restrict__ B) {
    const int ch = blockIdx.x, t = threadIdx.x;
    const int h = t >> 6, d = t & 63;
    const float tmax = ts1[h * NND + NND - 1];
    float runA = cTA[(h * CH + ch) * D1 + d];
    float runB = cTB[(h * CH + ch) * D1 + d];
    const float totA = TotA[h * D1 + d];
    const int k0 = ch * CHR;
    float v[CHR], wa[CHR], wb[CHR];
#pragma unroll
    for (int r = 0; r < CHR; r++) {
        float u = ts1[h * NND + k0 + r] - tmax;
        wa[r] = __expf(u); wb[r] = __expf(LEAKY * u);
        int j = perm1[h * NND + k0 + r];
        v[r] = Wx1[(size_t)j * HID + h * D1 + d];
    }
#pragma unroll
    for (int r = 0; r < CHR; r++) {
        size_t o = ((size_t)(h * NP1 + k0 + r)) * D1 + d;
        A[o] = totA - runA;
        B[o] = runB;
        runA += wa[r] * v[r];
        runB += wb[r] * v[r];
    }
    if (ch == CH - 1) {
        size_t o = ((size_t)(h * NP1 + NND)) * D1 + d;
        A[o] = totA - runA;
        B[o] = runB;
    }
}

// ---------------- k6: lookup1 -> h1 bf16 k-panels + fused escore2 ----------------
__global__ __launch_bounds__(256) void k6_lookup1(const float* __restrict__ es,
        const float* __restrict__ ts,
        const float* __restrict__ A, const float* __restrict__ Bv,
        const float* __restrict__ SA, const float* __restrict__ SB,
        const float* __restrict__ w_es, const float* __restrict__ w_et,
        unsigned short* __restrict__ h1p,
        float* __restrict__ es2, float* __restrict__ et2) {
    __shared__ float hbuf[256];
    const int i = blockIdx.x, t = threadIdx.x;
    const int h = t >> 6, d = t & 63;
    const int lane = t & 63, wid = t >> 6;
    float c = es[h * NND + i];
    float tmax = ts[h * NND + NND - 1];
    float s = c + tmax;
    float m = (s >= 0.f) ? s : LEAKY * s;
    float al = __expf(s - m);
    float be = __expf(LEAKY * s - m);
    int k = lower_bound_f(ts + h * NND, -c);
    size_t o = ((size_t)(h * NP1 + k)) * D1 + d;
    float num = al * A[o] + be * Bv[o];
    float den = al * SA[h * NP1 + k] + be * SB[h * NP1 + k];
    float val = num / den;
    float hv = (val > 0.f) ? val : expm1f(val);
    h1p[((size_t)(t >> 3) * NND + i) * 8 + (t & 7)] = f2bf(hv);
    hbuf[t] = hv;
    __syncthreads();
    float4 hv4 = *(const float4*)&hbuf[lane * 4];
    float4 we4 = *(const float4*)&w_es[wid * HID + lane * 4];
    float4 wt4 = *(const float4*)&w_et[wid * HID + lane * 4];
    float pes = hv4.x * we4.x + hv4.y * we4.y + hv4.z * we4.z + hv4.w * we4.w;
    float pet = hv4.x * wt4.x + hv4.y * wt4.y + hv4.z * wt4.z + hv4.w * wt4.w;
    pes = wave_sum(pes);
    pet = wave_sum(pet);
    if (lane == 0) {
        es2[wid * NND + i] = pes;
        et2[wid * NND + i] = pet;
    }
}

// ---------------- k7: gemm2 plain-bf16 128x64 tile, panel staging | sort2 ----------------
__global__ __launch_bounds__(256) void k7_gemm2_sort2(
        const unsigned short* __restrict__ h1p, const unsigned short* __restrict__ W2p,
        float* __restrict__ Wx2,
        const float* __restrict__ et2, float* __restrict__ ts2, int* __restrict__ perm2) {
    union SM7 {
        struct { unsigned short Ah[512][8], Bh[256][8]; } g;
        struct { unsigned key[NND]; int pr[64]; } s;
    };
    __shared__ SM7 sm;
    const int bid = blockIdx.x, t = threadIdx.x;
    if (bid >= 512) {
        sort_block(sm.s.key, sm.s.pr, et2, ts2, perm2,
                   (bid - 512) >> 6, ((bid - 512) & 63) * 64, t);
        return;
    }
    const int lane = t & 63, w = t >> 6;
    const int n0 = (bid & 15) * 64, m0 = (bid >> 4) * 128;
    const int fr = lane & 15, kg = lane >> 4;
    f32x4 z4 = {0.f, 0.f, 0.f, 0.f};
    f32x4 acc[2][4] = {{z4, z4, z4, z4}, {z4, z4, z4, z4}};
    u16x8 rA[2], rB;
    auto load_step = [&](int k0) {
        int kgrp = (k0 >> 3) + w;
#pragma unroll
        for (int rr = 0; rr < 2; rr++)
            rA[rr] = *(const u16x8*)&h1p[((size_t)kgrp * NND + m0 + rr * 64 + lane) * 8];
        rB = *(const u16x8*)&W2p[((size_t)kgrp * C2 + n0 + lane) * 8];
    };
    load_step(0);
    for (int k0 = 0; k0 < HID; k0 += 32) {
#pragma unroll
        for (int rr = 0; rr < 2; rr++)
            *(u16x8*)&sm.g.Ah[w * 128 + rr * 64 + lane][0] = rA[rr];
        *(u16x8*)&sm.g.Bh[w * 64 + lane][0] = rB;
        __syncthreads();
        if (k0 + 32 < HID) load_step(k0 + 32);
        bf16x8 ah[2], bh[4];
#pragma unroll
        for (int mb = 0; mb < 2; mb++)
            ah[mb] = *(bf16x8*)&sm.g.Ah[kg * 128 + w * 32 + mb * 16 + fr][0];
#pragma unroll
        for (int nb = 0; nb < 4; nb++)
            bh[nb] = *(bf16x8*)&sm.g.Bh[kg * 64 + nb * 16 + fr][0];
#pragma unroll
        for (int mb = 0; mb < 2; mb++)
#pragma unroll
            for (int nb = 0; nb < 4; nb++)
                MM(ah[mb], bh[nb], acc[mb][nb]);
        __syncthreads();
    }
#pragma unroll
    for (int mb = 0; mb < 2; mb++)
#pragma unroll
        for (int r = 0; r < 4; r++) {
            int row = m0 + w * 32 + mb * 16 + kg * 4 + r;
#pragma unroll
            for (int nb = 0; nb < 4; nb++)
                Wx2[(size_t)row * C2 + n0 + nb * 16 + fr] = acc[mb][nb][r];
        }
}

// ---------------- k8: layer-2 scan p1 + wprep2 ----------------
__global__ __launch_bounds__(256) void k8_scan2_p1(const float* __restrict__ Wx2,
        const float* __restrict__ ts2, const int* __restrict__ perm2,
        float* __restrict__ cTA, float* __restrict__ cTB,
        float* __restrict__ SA, float* __restrict__ SB) {
    __shared__ float swA[4], swB[4];
    const int bid = blockIdx.x, t = threadIdx.x;
    if (bid >= 2048) { wprep_block(ts2, SA, SB, bid - 2048, t, swA, swB); return; }
    const int ch = bid & (CH - 1), h = bid >> 9;
    const int d = t, k0 = ch * CHR;
    const float tmax = ts2[h * NND + NND - 1];
    float aA = 0.f, aB = 0.f;
#pragma unroll
    for (int r = 0; r < CHR; r++) {
        float u = ts2[h * NND + k0 + r] - tmax;
        float wa = __expf(u), wb = __expf(LEAKY * u);
        int j = perm2[h * NND + k0 + r];
        float v = Wx2[(size_t)j * C2 + h * D2 + d];
        aA += wa * v; aB += wb * v;
    }
    cTA[(h * CH + ch) * D2 + d] = aA;
    cTB[(h * CH + ch) * D2 + d] = aB;
}

// ---------------- k10: layer-2 scan p3 -> packed bf16 (A | B<<16) ----------------
__global__ __launch_bounds__(256) void k10_scan2_p3(const float* __restrict__ Wx2,
        const float* __restrict__ ts2, const int* __restrict__ perm2,
        const float* __restrict__ cTA, const float* __restrict__ cTB,
        const float* __restrict__ TotA,
        unsigned* __restrict__ AB) {
    const int bid = blockIdx.x, t = threadIdx.x;
    const int ch = bid & (CH - 1), h = bid >> 9;
    const int d = t;
    const float tmax = ts2[h * NND + NND - 1];
    float runA = cTA[(h * CH + ch) * D2 + d];
    float runB = cTB[(h * CH + ch) * D2 + d];
    const float totA = TotA[h * D2 + d];
    const int k0 = ch * CHR;
    float v[CHR], wa[CHR], wb[CHR];
#pragma unroll
    for (int r = 0; r < CHR; r++) {
        float u = ts2[h * NND + k0 + r] - tmax;
        wa[r] = __expf(u); wb[r] = __expf(LEAKY * u);
        int j = perm2[h * NND + k0 + r];
        v[r] = Wx2[(size_t)j * C2 + h * D2 + d];
    }
#pragma unroll
    for (int r = 0; r < CHR; r++) {
        size_t o = ((size_t)(h * NP1 + k0 + r)) * D2 + d;
        AB[o] = (unsigned)f2bf(totA - runA) | ((unsigned)f2bf(runB) << 16);
        runA += wa[r] * v[r];
        runB += wb[r] * v[r];
    }
    if (ch == CH - 1) {
        size_t o = ((size_t)(h * NP1 + NND)) * D2 + d;
        AB[o] = (unsigned)f2bf(totA - runA) | ((unsigned)f2bf(runB) << 16);
    }
}

// ---------------- k11: lookup2 (packed A/B; head-mean + ELU + LayerNorm) ----------------
__global__ __launch_bounds__(256) void k11_lookup2(const float* __restrict__ es,
        const float* __restrict__ ts,
        const unsigned* __restrict__ AB,
        const float* __restrict__ SA, const float* __restrict__ SB,
        const float* __restrict__ gamma, const float* __restrict__ betap,
        float* __restrict__ out) {
    __shared__ float red[4];
    const int i = blockIdx.x;
    const int t = threadIdx.x;
    const int wid = t >> 6, lane = t & 63;
    float acc = 0.f;
#pragma unroll
    for (int h = 0; h < HEADS; h++) {
        float c = es[h * NND + i];
        float tmax = ts[h * NND + NND - 1];
        float s = c + tmax;
        float m = (s >= 0.f) ? s : LEAKY * s;
        float al = __expf(s - m);
        float be = __expf(LEAKY * s - m);
        int k = lower_bound_f(ts + h * NND, -c);
        size_t o = ((size_t)(h * NP1 + k)) * D2 + t;
        unsigned u = AB[o];
        float Av = bf2f((unsigned short)(u & 0xFFFFu));
        float Bu = bf2f((unsigned short)(u >> 16));
        float num = al * Av + be * Bu;
        float den = al * SA[h * NP1 + k] + be * SB[h * NP1 + k];
        acc += num / den;
    }
    acc *= 0.25f;
    float xv = (acc > 0.f) ? acc : expm1f(acc);
    float sv = wave_sum(xv);
    if (lane == 0) red[wid] = sv;
    __syncthreads();
    float mu = (red[0] + red[1] + red[2] + red[3]) * (1.f / 256.f);
    __syncthreads();
    float dv = xv - mu;
    float s2 = wave_sum(dv * dv);
    if (lane == 0) red[wid] = s2;
    __syncthreads();
    float var = (red[0] + red[1] + red[2] + red[3]) * (1.f / 256.f);
    out[i * D2 + t] = gamma[t] * dv * rsqrtf(var + LN_EPS) + betap[t];
}

extern "C" void kernel_launch(void* const* d_in, const int* in_sizes, int n_in,
                              void* d_out, int out_size, void* d_ws, size_t ws_size,
                              hipStream_t stream) {
    const float* x     = (const float*)d_in[0];
    const float* W1    = (const float*)d_in[1];
    const float* attn1 = (const float*)d_in[2];
    const float* W2    = (const float*)d_in[3];
    const float* attn2 = (const float*)d_in[4];
    const float* gamma = (const float*)d_in[5];
    const float* betap = (const float*)d_in[6];
    float* out = (float*)d_out;

    char* ws = (char*)d_ws;
    size_t off = 0;
    auto alloc = [&](size_t nbytes) -> void* {
        void* p = (void*)(ws + off);
        off += (nbytes + 255) & ~(size_t)255;
        return p;
    };

    float* Wx1 = (float*)alloc((size_t)NND * HID * 4);
    float* Wx2 = (float*)alloc((size_t)NND * C2 * 4);
    unsigned short* h1p = (unsigned short*)alloc((size_t)NND * HID * 2);
    float* es1 = (float*)alloc((size_t)HEADS * NND * 4);
    float* et1 = (float*)alloc((size_t)HEADS * NND * 4);
    float* es2 = (float*)alloc((size_t)HEADS * NND * 4);
    float* et2 = (float*)alloc((size_t)HEADS * NND * 4);
    float* ts1 = (float*)alloc((size_t)HEADS * NND * 4);
    float* ts2 = (float*)alloc((size_t)HEADS * NND * 4);
    int* perm1 = (int*)alloc((size_t)HEADS * NND * 4);
    int* perm2 = (int*)alloc((size_t)HEADS * NND * 4);
    float* A   = (float*)alloc((size_t)HEADS * NP1 * D1 * 4);
    float* B   = (float*)alloc((size_t)HEADS * NP1 * D1 * 4);
    unsigned* AB2 = (unsigned*)alloc((size_t)HEADS * NP1 * D2 * 4);
    float* SA  = (float*)alloc((size_t)HEADS * NP1 * 4);
    float* SB  = (float*)alloc((size_t)HEADS * NP1 * 4);
    float* cTA = (float*)alloc((size_t)HEADS * CH * D2 * 4);
    float* cTB = (float*)alloc((size_t)HEADS * CH * D2 * 4);
    float* TotA = (float*)alloc((size_t)HEADS * D2 * 4);
    float* TotB = (float*)alloc((size_t)HEADS * D2 * 4);
    unsigned short* W2p = (unsigned short*)alloc((size_t)262144 * 2);
    float* w_es = (float*)alloc((size_t)HEADS * HID * 4);
    float* w_et = (float*)alloc((size_t)HEADS * HID * 4);
    (void)ws_size; (void)in_sizes; (void)n_in; (void)out_size;

    // ---- layer 1 ----
    k1_gemm1_prep<<<832, 256, 0, stream>>>(x, W1, attn1, W2, attn2,
                                           Wx1, es1, et1, W2p, w_es, w_et);
    k2_sort<<<256, 256, 0, stream>>>(et1, ts1, perm1);
    k3_scan1_p1<<<CH + 4, 256, 0, stream>>>(Wx1, ts1, perm1, cTA, cTB, SA, SB);
    k_scan_p2<<<64, 256, 0, stream>>>(cTA, cTB, TotA, TotB, 6);
    k5_scan1_p3<<<CH, 256, 0, stream>>>(Wx1, ts1, perm1, cTA, cTB, TotA, A, B);
    k6_lookup1<<<NND, 256, 0, stream>>>(es1, ts1, A, B, SA, SB, w_es, w_et,
                                        h1p, es2, et2);

    // ---- layer 2 ----
    k7_gemm2_sort2<<<768, 256, 0, stream>>>(h1p, W2p, Wx2, et2, ts2, perm2);
    k8_scan2_p1<<<2052, 256, 0, stream>>>(Wx2, ts2, perm2, cTA, cTB, SA, SB);
    k_scan_p2<<<256, 256, 0, stream>>>(cTA, cTB, TotA, TotB, 8);
    k10_scan2_p3<<<2048, 256, 0, stream>>>(Wx2, ts2, perm2, cTA, cTB, TotA, AB2);
    k11_lookup2<<<NND, 256, 0, stream>>>(es2, ts2, AB2, SA, SB, gamma, betap, out);
}

// Round 15
// 147.799 us; speedup vs baseline: 1.1345x; 1.0081x over previous
//
#include <hip/hip_runtime.h>
#include <math.h>

#define NND 4096
#define SDIM 128
#define HEADS 4
#define D1 64
#define HID 256
#define D2 256
#define C2 1024
#define NP1 (NND + 1)
#define CH 512
#define CHR 8
#define LEAKY 0.2f
#define LN_EPS 1e-5f

typedef __attribute__((ext_vector_type(8))) short bf16x8;
typedef __attribute__((ext_vector_type(4))) float f32x4;
typedef __attribute__((ext_vector_type(8))) unsigned short u16x8;

__device__ __forceinline__ unsigned short f2bf(float f) {
    union { float f; unsigned u; } v; v.f = f;
    unsigned r = v.u + 0x7FFFu + ((v.u >> 16) & 1u);
    return (unsigned short)(r >> 16);
}
__device__ __forceinline__ float bf2f(unsigned short s) {
    union { unsigned u; float f; } v; v.u = ((unsigned)s) << 16; return v.f;
}
__device__ __forceinline__ float wave_sum(float v) {
#pragma unroll
    for (int o = 32; o > 0; o >>= 1) v += __shfl_xor(v, o, 64);
    return v;
}
__device__ __forceinline__ int lower_bound_f(const float* __restrict__ a, float x) {
    int lo = 0, hi = NND;
    while (lo < hi) {
        int mid = (lo + hi) >> 1;
        if (a[mid] < x) lo = mid + 1; else hi = mid;
    }
    return lo;
}
// fragment-linear chunk index: 16-row group, 8-k group
__device__ __forceinline__ int chunk_of(int row, int kg) {
    return ((row >> 4) << 6) + (kg << 4) + (row & 15);
}

#define MM(a, b, c) c = __builtin_amdgcn_mfma_f32_16x16x32_bf16(a, b, c, 0, 0, 0)

// ---------------- sort: rank of 64 elems/block vs all keys (vectorized b128 reads) -------
__device__ __forceinline__ void sort_block(unsigned* key, int* pr,
        const float* __restrict__ et,
        float* __restrict__ ts, int* __restrict__ perm, int h, int e0, int t) {
    for (int p = t; p < NND; p += 256) {
        unsigned u = __float_as_uint(et[h * NND + p]);
        key[p] = (u & 0x80000000u) ? ~u : (u | 0x80000000u);
    }
    if (t < 64) pr[t] = 0;
    __syncthreads();
    const int e = t & 63, sg = t >> 6;
    const int myIdx = e0 + e;
    const unsigned myU = key[myIdx];
    int rank = 0;
    const int kbeg = sg * (NND / 4);
    for (int kb = kbeg; kb < kbeg + NND / 4; kb += 16) {
        uint4 v0 = *(const uint4*)&key[kb];
        uint4 v1 = *(const uint4*)&key[kb + 4];
        uint4 v2 = *(const uint4*)&key[kb + 8];
        uint4 v3 = *(const uint4*)&key[kb + 12];
        unsigned vv[16] = {v0.x, v0.y, v0.z, v0.w, v1.x, v1.y, v1.z, v1.w,
                           v2.x, v2.y, v2.z, v2.w, v3.x, v3.y, v3.z, v3.w};
#pragma unroll
        for (int q = 0; q < 16; q++) {
            unsigned v = vv[q];
            rank += (int)(v < myU) + (int)((v == myU) & ((kb + q) < myIdx));
        }
    }
    atomicAdd(&pr[e], rank);
    __syncthreads();
    if (t < 64) {
        int r = pr[t];
        unsigned u = key[e0 + t];
        float f = (u & 0x80000000u) ? __uint_as_float(u ^ 0x80000000u)
                                    : __uint_as_float(~u);
        ts[h * NND + r] = f;
        perm[h * NND + r] = e0 + t;
    }
}

// ---------------- per-head scalar weight scan ----------------
__device__ __forceinline__ void wprep_block(const float* __restrict__ ts,
        float* __restrict__ SA, float* __restrict__ SB, int h, int t,
        float* swA, float* swB) {
    const int lane = t & 63, w = t >> 6;
    const float tmax = ts[h * NND + NND - 1];
    float a[16], b[16];
    float la = 0.f, lb = 0.f;
    const int kb = t * 16;
#pragma unroll
    for (int q = 0; q < 16; q++) {
        float u = ts[h * NND + kb + q] - tmax;
        a[q] = __expf(u); b[q] = __expf(LEAKY * u);
        la += a[q]; lb += b[q];
    }
    float sa = la, sb = lb;
#pragma unroll
    for (int o = 1; o < 64; o <<= 1) {
        float ua = __shfl_up(sa, o, 64);
        float ub = __shfl_up(sb, o, 64);
        if (lane >= o) { sa += ua; sb += ub; }
    }
    if (lane == 63) { swA[w] = sa; swB[w] = sb; }
    __syncthreads();
    float baseA = 0.f, baseB = 0.f, totA = 0.f, totB = 0.f;
#pragma unroll
    for (int ww = 0; ww < 4; ww++) {
        float va = swA[ww], vb = swB[ww];
        totA += va; totB += vb;
        if (ww < w) { baseA += va; baseB += vb; }
    }
    float preA = baseA + sa - la;
    float preB = baseB + sb - lb;
#pragma unroll
    for (int q = 0; q < 16; q++) {
        SA[h * NP1 + kb + q] = totA - preA;
        SB[h * NP1 + kb + q] = preB;
        preA += a[q]; preB += b[q];
    }
    if (t == 255) { SA[h * NP1 + NND] = 0.f; SB[h * NP1 + NND] = totB; }
}

// ---------------- k1: gemm1 plain-bf16 (fused escore1) | W2 panel-prep | attn2 fold ------
__global__ __launch_bounds__(256) void k1_gemm1_prep(
        const float* __restrict__ x, const float* __restrict__ W1,
        const float* __restrict__ attn1,
        const float* __restrict__ W2, const float* __restrict__ attn2,
        float* __restrict__ Wx1, float* __restrict__ es1, float* __restrict__ et1,
        unsigned short* __restrict__ W2p,
        float* __restrict__ w_es, float* __restrict__ w_et) {
    union SM1 {
        struct {
            unsigned short Ah[256][8], Bh[256][8];
            float esP[2][2][32], etP[2][2][32];
        } g;
        float tile[64][65];
    };
    __shared__ SM1 sm;
    const int bid = blockIdx.x, t = threadIdx.x;
    if (bid < 256) {
        const int lane = t & 63, w = t >> 6;
        const int wm = w >> 1, wn = w & 1;
        const int h = bid & 3, n0 = h * 64, m0 = (bid >> 2) * 64;
        const int fr = lane & 15, kg = lane >> 4;
        const int arow = t >> 2, akg = t & 3;
        const int ac = chunk_of(arow, akg);
        const int brow = t & 63, bkg = t >> 6;
        const int bc = chunk_of(brow, bkg);
        f32x4 z4 = {0.f, 0.f, 0.f, 0.f};
        f32x4 acc[2][2] = {{z4, z4}, {z4, z4}};
        for (int k0 = 0; k0 < SDIM; k0 += 32) {
            {   // A: 8 floats of row arow -> bf16
                float fv[8];
                *(float4*)&fv[0] = *(const float4*)&x[(size_t)(m0 + arow) * SDIM + k0 + akg * 8];
                *(float4*)&fv[4] = *(const float4*)&x[(size_t)(m0 + arow) * SDIM + k0 + akg * 8 + 4];
                u16x8 ph;
#pragma unroll
                for (int i = 0; i < 8; i++) ph[i] = f2bf(fv[i]);
                *(u16x8*)&sm.g.Ah[ac][0] = ph;
            }
            {   // B: 8 k's of column n0+brow -> bf16
                u16x8 ph;
#pragma unroll
                for (int i = 0; i < 8; i++)
                    ph[i] = f2bf(W1[(size_t)(k0 + bkg * 8 + i) * HID + n0 + brow]);
                *(u16x8*)&sm.g.Bh[bc][0] = ph;
            }
            __syncthreads();
            bf16x8 ah0 = *(bf16x8*)&sm.g.Ah[wm * 128 + lane][0];
            bf16x8 ah1 = *(bf16x8*)&sm.g.Ah[wm * 128 + 64 + lane][0];
            bf16x8 bh0 = *(bf16x8*)&sm.g.Bh[wn * 128 + lane][0];
            bf16x8 bh1 = *(bf16x8*)&sm.g.Bh[wn * 128 + 64 + lane][0];
            MM(ah0, bh0, acc[0][0]);
            MM(ah0, bh1, acc[0][1]);
            MM(ah1, bh0, acc[1][0]);
            MM(ah1, bh1, acc[1][1]);
            __syncthreads();
        }
        const float as0 = attn1[h * 128 + wn * 32 + fr];
        const float as1 = attn1[h * 128 + wn * 32 + 16 + fr];
        const float at0 = attn1[h * 128 + 64 + wn * 32 + fr];
        const float at1 = attn1[h * 128 + 64 + wn * 32 + 16 + fr];
#pragma unroll
        for (int mb = 0; mb < 2; mb++) {
#pragma unroll
            for (int r = 0; r < 4; r++) {
                int row = m0 + wm * 32 + mb * 16 + kg * 4 + r;
#pragma unroll
                for (int nb = 0; nb < 2; nb++)
                    Wx1[(size_t)row * HID + n0 + wn * 32 + nb * 16 + fr] = acc[mb][nb][r];
                float ve = acc[mb][0][r] * as0 + acc[mb][1][r] * as1;
                float vt = acc[mb][0][r] * at0 + acc[mb][1][r] * at1;
#pragma unroll
                for (int msk = 1; msk < 16; msk <<= 1) {
                    ve += __shfl_xor(ve, msk, 64);
                    vt += __shfl_xor(vt, msk, 64);
                }
                if (fr == 0) {
                    sm.g.esP[wm][wn][mb * 16 + kg * 4 + r] = ve;
                    sm.g.etP[wm][wn][mb * 16 + kg * 4 + r] = vt;
                }
            }
        }
        __syncthreads();
        if (t < 64) {
            int wmm = t >> 5, ri = t & 31;
            es1[h * NND + m0 + t] = sm.g.esP[wmm][0][ri] + sm.g.esP[wmm][1][ri];
            et1[h * NND + m0 + t] = sm.g.etP[wmm][0][ri] + sm.g.etP[wmm][1][ri];
        }
    } else if (bid < 320) {
        const int tb = bid - 256;
        const int tk = tb & 3, tn = tb >> 2;
#pragma unroll
        for (int q = 0; q < 16; q++) {
            int idx = q * 256 + t;
            int kr = idx >> 6, nc = idx & 63;
            sm.tile[kr][nc] = W2[(size_t)(tk * 64 + kr) * C2 + tn * 64 + nc];
        }
        __syncthreads();
#pragma unroll
        for (int q = 0; q < 16; q++) {
            int idx = q * 256 + t;
            int nr = idx >> 6, kc = idx & 63;
            float v = sm.tile[kc][nr];
            int kglob = tk * 64 + kc;
            size_t o = ((size_t)(kglob >> 3) * C2 + tn * 64 + nr) * 8 + (kglob & 7);
            W2p[o] = f2bf(v);
        }
    } else {
        int g = (bid - 320) * 4 + (t >> 6);
        int lane = t & 63;
        int k = g & 255, hs = g >> 8, h = hs >> 1, sel = hs & 1;
        float acc = 0.f;
#pragma unroll
        for (int qq = 0; qq < 4; qq++)
            acc += W2[(size_t)k * C2 + h * 256 + qq * 64 + lane] *
                   attn2[h * 512 + sel * 256 + qq * 64 + lane];
        acc = wave_sum(acc);
        if (lane == 0) {
            if (sel) w_et[h * 256 + k] = acc;
            else     w_es[h * 256 + k] = acc;
        }
    }
}

// ---------------- k2: sort (layer 1) ----------------
__global__ __launch_bounds__(256) void k2_sort(const float* __restrict__ et,
        float* __restrict__ ts, int* __restrict__ perm) {
    __shared__ unsigned key[NND];
    __shared__ int pr[64];
    const int bid = blockIdx.x, t = threadIdx.x;
    sort_block(key, pr, et, ts, perm, bid >> 6, (bid & 63) * 64, t);
}

// ---------------- k3: layer-1 scan p1 (4h x 64d) + wprep1 ----------------
__global__ __launch_bounds__(256) void k3_scan1_p1(const float* __restrict__ Wx1,
        const float* __restrict__ ts1, const int* __restrict__ perm1,
        float* __restrict__ cTA, float* __restrict__ cTB,
        float* __restrict__ SA, float* __restrict__ SB) {
    __shared__ float swA[4], swB[4];
    const int bid = blockIdx.x, t = threadIdx.x;
    if (bid >= CH) { wprep_block(ts1, SA, SB, bid - CH, t, swA, swB); return; }
    const int h = t >> 6, d = t & 63;
    const int k0 = bid * CHR;
    const float tmax = ts1[h * NND + NND - 1];
    float aA = 0.f, aB = 0.f;
#pragma unroll
    for (int r = 0; r < CHR; r++) {
        float u = ts1[h * NND + k0 + r] - tmax;
        float wa = __expf(u), wb = __expf(LEAKY * u);
        int j = perm1[h * NND + k0 + r];
        float v = Wx1[(size_t)j * HID + h * D1 + d];
        aA += wa * v; aB += wb * v;
    }
    cTA[(h * CH + bid) * D1 + d] = aA;
    cTB[(h * CH + bid) * D1 + d] = aB;
}

// ---------------- p2: wave-parallel exclusive scan of chunk totals (in place) ------------
__global__ __launch_bounds__(256) void k_scan_p2(float* __restrict__ cTA,
        float* __restrict__ cTB, float* __restrict__ TotA, float* __restrict__ TotB,
        int logD) {
    const int t = threadIdx.x;
    const int lane = t & 63, w = t >> 6;
    const int D = 1 << logD;
    const int col = blockIdx.x * 4 + w;
    const int h = col >> logD, d = col & (D - 1);
    const size_t base = (size_t)h * CH * D + d;
    float vA[8], vB[8];
#pragma unroll
    for (int q = 0; q < 8; q++) {
        size_t o = base + (size_t)(lane * 8 + q) * D;
        vA[q] = cTA[o];
        vB[q] = cTB[o];
    }
    float laA = 0.f, laB = 0.f;
#pragma unroll
    for (int q = 0; q < 8; q++) { laA += vA[q]; laB += vB[q]; }
    float sA = laA, sB = laB;
#pragma unroll
    for (int o = 1; o < 64; o <<= 1) {
        float uA = __shfl_up(sA, o, 64);
        float uB = __shfl_up(sB, o, 64);
        if (lane >= o) { sA += uA; sB += uB; }
    }
    float totA = __shfl(sA, 63, 64);
    float totB = __shfl(sB, 63, 64);
    float runA = sA - laA, runB = sB - laB;
#pragma unroll
    for (int q = 0; q < 8; q++) {
        size_t o = base + (size_t)(lane * 8 + q) * D;
        float tA = vA[q], tB = vB[q];
        cTA[o] = runA;
        cTB[o] = runB;
        runA += tA; runB += tB;
    }
    if (lane == 0) {
        TotA[h * D + d] = totA;
        TotB[h * D + d] = totB;
    }
}

// ---------------- k5: layer-1 scan p3 (fp32 A/B) ----------------
__global__ __launch_bounds__(256) void k5_scan1_p3(const float* __restrict__ Wx1,
        const float* __restrict__ ts1, const int* __restrict__ perm1,
        const float* __restrict__ cTA, const float* __restrict__ cTB,
        const float* __restrict__ TotA,
        float* __restrict__ A, float* __restrict__ B) {
    const int ch = blockIdx.x, t = threadIdx.x;
    const int h = t >> 6, d = t & 63;
    const float tmax = ts1[h * NND + NND - 1];
    float runA = cTA[(h * CH + ch) * D1 + d];
    float runB = cTB[(h * CH + ch) * D1 + d];
    const float totA = TotA[h * D1 + d];
    const int k0 = ch * CHR;
    float v[CHR], wa[CHR], wb[CHR];
#pragma unroll
    for (int r = 0; r < CHR; r++) {
        float u = ts1[h * NND + k0 + r] - tmax;
        wa[r] = __expf(u); wb[r] = __expf(LEAKY * u);
        int j = perm1[h * NND + k0 + r];
        v[r] = Wx1[(size_t)j * HID + h * D1 + d];
    }
#pragma unroll
    for (int r = 0; r < CHR; r++) {
        size_t o = ((size_t)(h * NP1 + k0 + r)) * D1 + d;
        A[o] = totA - runA;
        B[o] = runB;
        runA += wa[r] * v[r];
        runB += wb[r] * v[r];
    }
    if (ch == CH - 1) {
        size_t o = ((size_t)(h * NP1 + NND)) * D1 + d;
        A[o] = totA - runA;
        B[o] = runB;
    }
}

// ---------------- k6: lookup1 -> h1 bf16 k-panels + fused escore2 ----------------
__global__ __launch_bounds__(256) void k6_lookup1(const float* __restrict__ es,
        const float* __restrict__ ts,
        const float* __restrict__ A, const float* __restrict__ Bv,
        const float* __restrict__ SA, const float* __restrict__ SB,
        const float* __restrict__ w_es, const float* __restrict__ w_et,
        unsigned short* __restrict__ h1p,
        float* __restrict__ es2, float* __restrict__ et2) {
    __shared__ float hbuf[256];
    const int i = blockIdx.x, t = threadIdx.x;
    const int h = t >> 6, d = t & 63;
    const int lane = t & 63, wid = t >> 6;
    float c = es[h * NND + i];
    float tmax = ts[h * NND + NND - 1];
    float s = c + tmax;
    float m = (s >= 0.f) ? s : LEAKY * s;
    float al = __expf(s - m);
    float be = __expf(LEAKY * s - m);
    int k = lower_bound_f(ts + h * NND, -c);
    size_t o = ((size_t)(h * NP1 + k)) * D1 + d;
    float num = al * A[o] + be * Bv[o];
    float den = al * SA[h * NP1 + k] + be * SB[h * NP1 + k];
    float val = num / den;
    float hv = (val > 0.f) ? val : expm1f(val);
    h1p[((size_t)(t >> 3) * NND + i) * 8 + (t & 7)] = f2bf(hv);
    hbuf[t] = hv;
    __syncthreads();
    float4 hv4 = *(const float4*)&hbuf[lane * 4];
    float4 we4 = *(const float4*)&w_es[wid * HID + lane * 4];
    float4 wt4 = *(const float4*)&w_et[wid * HID + lane * 4];
    float pes = hv4.x * we4.x + hv4.y * we4.y + hv4.z * we4.z + hv4.w * we4.w;
    float pet = hv4.x * wt4.x + hv4.y * wt4.y + hv4.z * wt4.z + hv4.w * wt4.w;
    pes = wave_sum(pes);
    pet = wave_sum(pet);
    if (lane == 0) {
        es2[wid * NND + i] = pes;
        et2[wid * NND + i] = pet;
    }
}

// ---------------- k7: gemm2 plain-bf16 128x64 tile, panel staging | sort2 ----------------
__global__ __launch_bounds__(256) void k7_gemm2_sort2(
        const unsigned short* __restrict__ h1p, const unsigned short* __restrict__ W2p,
        float* __restrict__ Wx2,
        const float* __restrict__ et2, float* __restrict__ ts2, int* __restrict__ perm2) {
    union SM7 {
        struct { unsigned short Ah[512][8], Bh[256][8]; } g;
        struct { unsigned key[NND]; int pr[64]; } s;
    };
    __shared__ SM7 sm;
    const int bid = blockIdx.x, t = threadIdx.x;
    if (bid >= 512) {
        sort_block(sm.s.key, sm.s.pr, et2, ts2, perm2,
                   (bid - 512) >> 6, ((bid - 512) & 63) * 64, t);
        return;
    }
    const int lane = t & 63, w = t >> 6;
    const int n0 = (bid & 15) * 64, m0 = (bid >> 4) * 128;
    const int fr = lane & 15, kg = lane >> 4;
    f32x4 z4 = {0.f, 0.f, 0.f, 0.f};
    f32x4 acc[2][4] = {{z4, z4, z4, z4}, {z4, z4, z4, z4}};
    u16x8 rA[2], rB;
    auto load_step = [&](int k0) {
        int kgrp = (k0 >> 3) + w;
#pragma unroll
        for (int rr = 0; rr < 2; rr++)
            rA[rr] = *(const u16x8*)&h1p[((size_t)kgrp * NND + m0 + rr * 64 + lane) * 8];
        rB = *(const u16x8*)&W2p[((size_t)kgrp * C2 + n0 + lane) * 8];
    };
    load_step(0);
    for (int k0 = 0; k0 < HID; k0 += 32) {
#pragma unroll
        for (int rr = 0; rr < 2; rr++)
            *(u16x8*)&sm.g.Ah[w * 128 + rr * 64 + lane][0] = rA[rr];
        *(u16x8*)&sm.g.Bh[w * 64 + lane][0] = rB;
        __syncthreads();
        if (k0 + 32 < HID) load_step(k0 + 32);
        bf16x8 ah[2], bh[4];
#pragma unroll
        for (int mb = 0; mb < 2; mb++)
            ah[mb] = *(bf16x8*)&sm.g.Ah[kg * 128 + w * 32 + mb * 16 + fr][0];
#pragma unroll
        for (int nb = 0; nb < 4; nb++)
            bh[nb] = *(bf16x8*)&sm.g.Bh[kg * 64 + nb * 16 + fr][0];
#pragma unroll
        for (int mb = 0; mb < 2; mb++)
#pragma unroll
            for (int nb = 0; nb < 4; nb++)
                MM(ah[mb], bh[nb], acc[mb][nb]);
        __syncthreads();
    }
#pragma unroll
    for (int mb = 0; mb < 2; mb++)
#pragma unroll
        for (int r = 0; r < 4; r++) {
            int row = m0 + w * 32 + mb * 16 + kg * 4 + r;
#pragma unroll
            for (int nb = 0; nb < 4; nb++)
                Wx2[(size_t)row * C2 + n0 + nb * 16 + fr] = acc[mb][nb][r];
        }
}

// ---------------- k8: layer-2 scan p1 + wprep2 ----------------
__global__ __launch_bounds__(256) void k8_scan2_p1(const float* __restrict__ Wx2,
        const float* __restrict__ ts2, const int* __restrict__ perm2,
        float* __restrict__ cTA, float* __restrict__ cTB,
        float* __restrict__ SA, float* __restrict__ SB) {
    __shared__ float swA[4], swB[4];
    const int bid = blockIdx.x, t = threadIdx.x;
    if (bid >= 2048) { wprep_block(ts2, SA, SB, bid - 2048, t, swA, swB); return; }
    const int ch = bid & (CH - 1), h = bid >> 9;
    const int d = t, k0 = ch * CHR;
    const float tmax = ts2[h * NND + NND - 1];
    float aA = 0.f, aB = 0.f;
#pragma unroll
    for (int r = 0; r < CHR; r++) {
        float u = ts2[h * NND + k0 + r] - tmax;
        float wa = __expf(u), wb = __expf(LEAKY * u);
        int j = perm2[h * NND + k0 + r];
        float v = Wx2[(size_t)j * C2 + h * D2 + d];
        aA += wa * v; aB += wb * v;
    }
    cTA[(h * CH + ch) * D2 + d] = aA;
    cTB[(h * CH + ch) * D2 + d] = aB;
}

// ---------------- k10: layer-2 scan p3 -> packed bf16 (A | B<<16) ----------------
__global__ __launch_bounds__(256) void k10_scan2_p3(const float* __restrict__ Wx2,
        const float* __restrict__ ts2, const int* __restrict__ perm2,
        const float* __restrict__ cTA, const float* __restrict__ cTB,
        const float* __restrict__ TotA,
        unsigned* __restrict__ AB) {
    const int bid = blockIdx.x, t = threadIdx.x;
    const int ch = bid & (CH - 1), h = bid >> 9;
    const int d = t;
    const float tmax = ts2[h * NND + NND - 1];
    float runA = cTA[(h * CH + ch) * D2 + d];
    float runB = cTB[(h * CH + ch) * D2 + d];
    const float totA = TotA[h * D2 + d];
    const int k0 = ch * CHR;
    float v[CHR], wa[CHR], wb[CHR];
#pragma unroll
    for (int r = 0; r < CHR; r++) {
        float u = ts2[h * NND + k0 + r] - tmax;
        wa[r] = __expf(u); wb[r] = __expf(LEAKY * u);
        int j = perm2[h * NND + k0 + r];
        v[r] = Wx2[(size_t)j * C2 + h * D2 + d];
    }
#pragma unroll
    for (int r = 0; r < CHR; r++) {
        size_t o = ((size_t)(h * NP1 + k0 + r)) * D2 + d;
        AB[o] = (unsigned)f2bf(totA - runA) | ((unsigned)f2bf(runB) << 16);
        runA += wa[r] * v[r];
        runB += wb[r] * v[r];
    }
    if (ch == CH - 1) {
        size_t o = ((size_t)(h * NP1 + NND)) * D2 + d;
        AB[o] = (unsigned)f2bf(totA - runA) | ((unsigned)f2bf(runB) << 16);
    }
}

// ---------------- k11: lookup2 (packed A/B; head-mean + ELU + LayerNorm) ----------------
__global__ __launch_bounds__(256) void k11_lookup2(const float* __restrict__ es,
        const float* __restrict__ ts,
        const unsigned* __restrict__ AB,
        const float* __restrict__ SA, const float* __restrict__ SB,
        const float* __restrict__ gamma, const float* __restrict__ betap,
        float* __restrict__ out) {
    __shared__ float red[4];
    const int i = blockIdx.x;
    const int t = threadIdx.x;
    const int wid = t >> 6, lane = t & 63;
    float acc = 0.f;
#pragma unroll
    for (int h = 0; h < HEADS; h++) {
        float c = es[h * NND + i];
        float tmax = ts[h * NND + NND - 1];
        float s = c + tmax;
        float m = (s >= 0.f) ? s : LEAKY * s;
        float al = __expf(s - m);
        float be = __expf(LEAKY * s - m);
        int k = lower_bound_f(ts + h * NND, -c);
        size_t o = ((size_t)(h * NP1 + k)) * D2 + t;
        unsigned u = AB[o];
        float Av = bf2f((unsigned short)(u & 0xFFFFu));
        float Bu = bf2f((unsigned short)(u >> 16));
        float num = al * Av + be * Bu;
        float den = al * SA[h * NP1 + k] + be * SB[h * NP1 + k];
        acc += num / den;
    }
    acc *= 0.25f;
    float xv = (acc > 0.f) ? acc : expm1f(acc);
    float sv = wave_sum(xv);
    if (lane == 0) red[wid] = sv;
    __syncthreads();
    float mu = (red[0] + red[1] + red[2] + red[3]) * (1.f / 256.f);
    __syncthreads();
    float dv = xv - mu;
    float s2 = wave_sum(dv * dv);
    if (lane == 0) red[wid] = s2;
    __syncthreads();
    float var = (red[0] + red[1] + red[2] + red[3]) * (1.f / 256.f);
    out[i * D2 + t] = gamma[t] * dv * rsqrtf(var + LN_EPS) + betap[t];
}

extern "C" void kernel_launch(void* const* d_in, const int* in_sizes, int n_in,
                              void* d_out, int out_size, void* d_ws, size_t ws_size,
                              hipStream_t stream) {
    const float* x     = (const float*)d_in[0];
    const float* W1    = (const float*)d_in[1];
    const float* attn1 = (const float*)d_in[2];
    const float* W2    = (const float*)d_in[3];
    const float* attn2 = (const float*)d_in[4];
    const float* gamma = (const float*)d_in[5];
    const float* betap = (const float*)d_in[6];
    float* out = (float*)d_out;

    char* ws = (char*)d_ws;
    size_t off = 0;
    auto alloc = [&](size_t nbytes) -> void* {
        void* p = (void*)(ws + off);
        off += (nbytes + 255) & ~(size_t)255;
        return p;
    };

    float* Wx1 = (float*)alloc((size_t)NND * HID * 4);
    float* Wx2 = (float*)alloc((size_t)NND * C2 * 4);
    unsigned short* h1p = (unsigned short*)alloc((size_t)NND * HID * 2);
    float* es1 = (float*)alloc((size_t)HEADS * NND * 4);
    float* et1 = (float*)alloc((size_t)HEADS * NND * 4);
    float* es2 = (float*)alloc((size_t)HEADS * NND * 4);
    float* et2 = (float*)alloc((size_t)HEADS * NND * 4);
    float* ts1 = (float*)alloc((size_t)HEADS * NND * 4);
    float* ts2 = (float*)alloc((size_t)HEADS * NND * 4);
    int* perm1 = (int*)alloc((size_t)HEADS * NND * 4);
    int* perm2 = (int*)alloc((size_t)HEADS * NND * 4);
    float* A   = (float*)alloc((size_t)HEADS * NP1 * D1 * 4);
    float* B   = (float*)alloc((size_t)HEADS * NP1 * D1 * 4);
    unsigned* AB2 = (unsigned*)alloc((size_t)HEADS * NP1 * D2 * 4);
    float* SA  = (float*)alloc((size_t)HEADS * NP1 * 4);
    float* SB  = (float*)alloc((size_t)HEADS * NP1 * 4);
    float* cTA = (float*)alloc((size_t)HEADS * CH * D2 * 4);
    float* cTB = (float*)alloc((size_t)HEADS * CH * D2 * 4);
    float* TotA = (float*)alloc((size_t)HEADS * D2 * 4);
    float* TotB = (float*)alloc((size_t)HEADS * D2 * 4);
    unsigned short* W2p = (unsigned short*)alloc((size_t)262144 * 2);
    float* w_es = (float*)alloc((size_t)HEADS * HID * 4);
    float* w_et = (float*)alloc((size_t)HEADS * HID * 4);
    (void)ws_size; (void)in_sizes; (void)n_in; (void)out_size;

    // ---- layer 1 ----
    k1_gemm1_prep<<<832, 256, 0, stream>>>(x, W1, attn1, W2, attn2,
                                           Wx1, es1, et1, W2p, w_es, w_et);
    k2_sort<<<256, 256, 0, stream>>>(et1, ts1, perm1);
    k3_scan1_p1<<<CH + 4, 256, 0, stream>>>(Wx1, ts1, perm1, cTA, cTB, SA, SB);
    k_scan_p2<<<64, 256, 0, stream>>>(cTA, cTB, TotA, TotB, 6);
    k5_scan1_p3<<<CH, 256, 0, stream>>>(Wx1, ts1, perm1, cTA, cTB, TotA, A, B);
    k6_lookup1<<<NND, 256, 0, stream>>>(es1, ts1, A, B, SA, SB, w_es, w_et,
                                        h1p, es2, et2);

    // ---- layer 2 ----
    k7_gemm2_sort2<<<768, 256, 0, stream>>>(h1p, W2p, Wx2, et2, ts2, perm2);
    k8_scan2_p1<<<2052, 256, 0, stream>>>(Wx2, ts2, perm2, cTA, cTB, SA, SB);
    k_scan_p2<<<256, 256, 0, stream>>>(cTA, cTB, TotA, TotB, 8);
    k10_scan2_p3<<<2048, 256, 0, stream>>>(Wx2, ts2, perm2, cTA, cTB, TotA, AB2);
    k11_lookup2<<<NND, 256, 0, stream>>>(es2, ts2, AB2, SA, SB, gamma, betap, out);
}

// Round 16
// 146.700 us; speedup vs baseline: 1.1430x; 1.0075x over previous
//
#include <hip/hip_runtime.h>
#include <math.h>

#define NND 4096
#define SDIM 128
#define HEADS 4
#define D1 64
#define HID 256
#define D2 256
#define C2 1024
#define NP1 (NND + 1)
#define CH 512
#define CHR 8
#define LEAKY 0.2f
#define LN_EPS 1e-5f

typedef __attribute__((ext_vector_type(8))) short bf16x8;
typedef __attribute__((ext_vector_type(4))) float f32x4;
typedef __attribute__((ext_vector_type(8))) unsigned short u16x8;

__device__ __forceinline__ unsigned short f2bf(float f) {
    union { float f; unsigned u; } v; v.f = f;
    unsigned r = v.u + 0x7FFFu + ((v.u >> 16) & 1u);
    return (unsigned short)(r >> 16);
}
__device__ __forceinline__ float bf2f(unsigned short s) {
    union { unsigned u; float f; } v; v.u = ((unsigned)s) << 16; return v.f;
}
__device__ __forceinline__ float wave_sum(float v) {
#pragma unroll
    for (int o = 32; o > 0; o >>= 1) v += __shfl_xor(v, o, 64);
    return v;
}
__device__ __forceinline__ int lower_bound_f(const float* __restrict__ a, float x) {
    int lo = 0, hi = NND;
    while (lo < hi) {
        int mid = (lo + hi) >> 1;
        if (a[mid] < x) lo = mid + 1; else hi = mid;
    }
    return lo;
}
// fragment-linear chunk index: 16-row group, 8-k group
__device__ __forceinline__ int chunk_of(int row, int kg) {
    return ((row >> 4) << 6) + (kg << 4) + (row & 15);
}

#define MM(a, b, c) c = __builtin_amdgcn_mfma_f32_16x16x32_bf16(a, b, c, 0, 0, 0)

// ---------------- sort: rank of 64 elems/block vs all keys (vectorized b128 reads) -------
__device__ __forceinline__ void sort_block(unsigned* key, int* pr,
        const float* __restrict__ et,
        float* __restrict__ ts, int* __restrict__ perm, int h, int e0, int t) {
    for (int p = t; p < NND; p += 256) {
        unsigned u = __float_as_uint(et[h * NND + p]);
        key[p] = (u & 0x80000000u) ? ~u : (u | 0x80000000u);
    }
    if (t < 64) pr[t] = 0;
    __syncthreads();
    const int e = t & 63, sg = t >> 6;
    const int myIdx = e0 + e;
    const unsigned myU = key[myIdx];
    int rank = 0;
    const int kbeg = sg * (NND / 4);
    for (int kb = kbeg; kb < kbeg + NND / 4; kb += 16) {
        uint4 v0 = *(const uint4*)&key[kb];
        uint4 v1 = *(const uint4*)&key[kb + 4];
        uint4 v2 = *(const uint4*)&key[kb + 8];
        uint4 v3 = *(const uint4*)&key[kb + 12];
        unsigned vv[16] = {v0.x, v0.y, v0.z, v0.w, v1.x, v1.y, v1.z, v1.w,
                           v2.x, v2.y, v2.z, v2.w, v3.x, v3.y, v3.z, v3.w};
#pragma unroll
        for (int q = 0; q < 16; q++) {
            unsigned v = vv[q];
            rank += (int)(v < myU) + (int)((v == myU) & ((kb + q) < myIdx));
        }
    }
    atomicAdd(&pr[e], rank);
    __syncthreads();
    if (t < 64) {
        int r = pr[t];
        unsigned u = key[e0 + t];
        float f = (u & 0x80000000u) ? __uint_as_float(u ^ 0x80000000u)
                                    : __uint_as_float(~u);
        ts[h * NND + r] = f;
        perm[h * NND + r] = e0 + t;
    }
}

// ---------------- per-head scalar weight scan ----------------
__device__ __forceinline__ void wprep_block(const float* __restrict__ ts,
        float* __restrict__ SA, float* __restrict__ SB, int h, int t,
        float* swA, float* swB) {
    const int lane = t & 63, w = t >> 6;
    const float tmax = ts[h * NND + NND - 1];
    float a[16], b[16];
    float la = 0.f, lb = 0.f;
    const int kb = t * 16;
#pragma unroll
    for (int q = 0; q < 16; q++) {
        float u = ts[h * NND + kb + q] - tmax;
        a[q] = __expf(u); b[q] = __expf(LEAKY * u);
        la += a[q]; lb += b[q];
    }
    float sa = la, sb = lb;
#pragma unroll
    for (int o = 1; o < 64; o <<= 1) {
        float ua = __shfl_up(sa, o, 64);
        float ub = __shfl_up(sb, o, 64);
        if (lane >= o) { sa += ua; sb += ub; }
    }
    if (lane == 63) { swA[w] = sa; swB[w] = sb; }
    __syncthreads();
    float baseA = 0.f, baseB = 0.f, totA = 0.f, totB = 0.f;
#pragma unroll
    for (int ww = 0; ww < 4; ww++) {
        float va = swA[ww], vb = swB[ww];
        totA += va; totB += vb;
        if (ww < w) { baseA += va; baseB += vb; }
    }
    float preA = baseA + sa - la;
    float preB = baseB + sb - lb;
#pragma unroll
    for (int q = 0; q < 16; q++) {
        SA[h * NP1 + kb + q] = totA - preA;
        SB[h * NP1 + kb + q] = preB;
        preA += a[q]; preB += b[q];
    }
    if (t == 255) { SA[h * NP1 + NND] = 0.f; SB[h * NP1 + NND] = totB; }
}

// ---------------- k1: gemm1 plain-bf16 (fused escore1) | W2 panel-prep | attn2 fold ------
__global__ __launch_bounds__(256) void k1_gemm1_prep(
        const float* __restrict__ x, const float* __restrict__ W1,
        const float* __restrict__ attn1,
        const float* __restrict__ W2, const float* __restrict__ attn2,
        float* __restrict__ Wx1, float* __restrict__ es1, float* __restrict__ et1,
        unsigned short* __restrict__ W2p,
        float* __restrict__ w_es, float* __restrict__ w_et) {
    union SM1 {
        struct {
            unsigned short Ah[256][8], Bh[256][8];
            float esP[2][2][32], etP[2][2][32];
        } g;
        float tile[64][65];
    };
    __shared__ SM1 sm;
    const int bid = blockIdx.x, t = threadIdx.x;
    if (bid < 256) {
        const int lane = t & 63, w = t >> 6;
        const int wm = w >> 1, wn = w & 1;
        const int h = bid & 3, n0 = h * 64, m0 = (bid >> 2) * 64;
        const int fr = lane & 15, kg = lane >> 4;
        const int arow = t >> 2, akg = t & 3;
        const int ac = chunk_of(arow, akg);
        const int brow = t & 63, bkg = t >> 6;
        const int bc = chunk_of(brow, bkg);
        f32x4 z4 = {0.f, 0.f, 0.f, 0.f};
        f32x4 acc[2][2] = {{z4, z4}, {z4, z4}};
        for (int k0 = 0; k0 < SDIM; k0 += 32) {
            {
                float fv[8];
                *(float4*)&fv[0] = *(const float4*)&x[(size_t)(m0 + arow) * SDIM + k0 + akg * 8];
                *(float4*)&fv[4] = *(const float4*)&x[(size_t)(m0 + arow) * SDIM + k0 + akg * 8 + 4];
                u16x8 ph;
#pragma unroll
                for (int i = 0; i < 8; i++) ph[i] = f2bf(fv[i]);
                *(u16x8*)&sm.g.Ah[ac][0] = ph;
            }
            {
                u16x8 ph;
#pragma unroll
                for (int i = 0; i < 8; i++)
                    ph[i] = f2bf(W1[(size_t)(k0 + bkg * 8 + i) * HID + n0 + brow]);
                *(u16x8*)&sm.g.Bh[bc][0] = ph;
            }
            __syncthreads();
            bf16x8 ah0 = *(bf16x8*)&sm.g.Ah[wm * 128 + lane][0];
            bf16x8 ah1 = *(bf16x8*)&sm.g.Ah[wm * 128 + 64 + lane][0];
            bf16x8 bh0 = *(bf16x8*)&sm.g.Bh[wn * 128 + lane][0];
            bf16x8 bh1 = *(bf16x8*)&sm.g.Bh[wn * 128 + 64 + lane][0];
            MM(ah0, bh0, acc[0][0]);
            MM(ah0, bh1, acc[0][1]);
            MM(ah1, bh0, acc[1][0]);
            MM(ah1, bh1, acc[1][1]);
            __syncthreads();
        }
        const float as0 = attn1[h * 128 + wn * 32 + fr];
        const float as1 = attn1[h * 128 + wn * 32 + 16 + fr];
        const float at0 = attn1[h * 128 + 64 + wn * 32 + fr];
        const float at1 = attn1[h * 128 + 64 + wn * 32 + 16 + fr];
#pragma unroll
        for (int mb = 0; mb < 2; mb++) {
#pragma unroll
            for (int r = 0; r < 4; r++) {
                int row = m0 + wm * 32 + mb * 16 + kg * 4 + r;
#pragma unroll
                for (int nb = 0; nb < 2; nb++)
                    Wx1[(size_t)row * HID + n0 + wn * 32 + nb * 16 + fr] = acc[mb][nb][r];
                float ve = acc[mb][0][r] * as0 + acc[mb][1][r] * as1;
                float vt = acc[mb][0][r] * at0 + acc[mb][1][r] * at1;
#pragma unroll
                for (int msk = 1; msk < 16; msk <<= 1) {
                    ve += __shfl_xor(ve, msk, 64);
                    vt += __shfl_xor(vt, msk, 64);
                }
                if (fr == 0) {
                    sm.g.esP[wm][wn][mb * 16 + kg * 4 + r] = ve;
                    sm.g.etP[wm][wn][mb * 16 + kg * 4 + r] = vt;
                }
            }
        }
        __syncthreads();
        if (t < 64) {
            int wmm = t >> 5, ri = t & 31;
            es1[h * NND + m0 + t] = sm.g.esP[wmm][0][ri] + sm.g.esP[wmm][1][ri];
            et1[h * NND + m0 + t] = sm.g.etP[wmm][0][ri] + sm.g.etP[wmm][1][ri];
        }
    } else if (bid < 320) {
        const int tb = bid - 256;
        const int tk = tb & 3, tn = tb >> 2;
#pragma unroll
        for (int q = 0; q < 16; q++) {
            int idx = q * 256 + t;
            int kr = idx >> 6, nc = idx & 63;
            sm.tile[kr][nc] = W2[(size_t)(tk * 64 + kr) * C2 + tn * 64 + nc];
        }
        __syncthreads();
#pragma unroll
        for (int q = 0; q < 16; q++) {
            int idx = q * 256 + t;
            int nr = idx >> 6, kc = idx & 63;
            float v = sm.tile[kc][nr];
            int kglob = tk * 64 + kc;
            size_t o = ((size_t)(kglob >> 3) * C2 + tn * 64 + nr) * 8 + (kglob & 7);
            W2p[o] = f2bf(v);
        }
    } else {
        int g = (bid - 320) * 4 + (t >> 6);
        int lane = t & 63;
        int k = g & 255, hs = g >> 8, h = hs >> 1, sel = hs & 1;
        float acc = 0.f;
#pragma unroll
        for (int qq = 0; qq < 4; qq++)
            acc += W2[(size_t)k * C2 + h * 256 + qq * 64 + lane] *
                   attn2[h * 512 + sel * 256 + qq * 64 + lane];
        acc = wave_sum(acc);
        if (lane == 0) {
            if (sel) w_et[h * 256 + k] = acc;
            else     w_es[h * 256 + k] = acc;
        }
    }
}

// ---------------- k2: sort (layer 1) ----------------
__global__ __launch_bounds__(256) void k2_sort(const float* __restrict__ et,
        float* __restrict__ ts, int* __restrict__ perm) {
    __shared__ unsigned key[NND];
    __shared__ int pr[64];
    const int bid = blockIdx.x, t = threadIdx.x;
    sort_block(key, pr, et, ts, perm, bid >> 6, (bid & 63) * 64, t);
}

// ---------------- k3: layer-1 scan p1 (4h x 64d) + wprep1 ----------------
__global__ __launch_bounds__(256) void k3_scan1_p1(const float* __restrict__ Wx1,
        const float* __restrict__ ts1, const int* __restrict__ perm1,
        float* __restrict__ cTA, float* __restrict__ cTB,
        float* __restrict__ SA, float* __restrict__ SB) {
    __shared__ float swA[4], swB[4];
    const int bid = blockIdx.x, t = threadIdx.x;
    if (bid >= CH) { wprep_block(ts1, SA, SB, bid - CH, t, swA, swB); return; }
    const int h = t >> 6, d = t & 63;
    const int k0 = bid * CHR;
    const float tmax = ts1[h * NND + NND - 1];
    float aA = 0.f, aB = 0.f;
#pragma unroll
    for (int r = 0; r < CHR; r++) {
        float u = ts1[h * NND + k0 + r] - tmax;
        float wa = __expf(u), wb = __expf(LEAKY * u);
        int j = perm1[h * NND + k0 + r];
        float v = Wx1[(size_t)j * HID + h * D1 + d];
        aA += wa * v; aB += wb * v;
    }
    cTA[(h * CH + bid) * D1 + d] = aA;
    cTB[(h * CH + bid) * D1 + d] = aB;
}

// ---------------- p2: wave-parallel exclusive scan of chunk totals (in place) ------------
__global__ __launch_bounds__(256) void k_scan_p2(float* __restrict__ cTA,
        float* __restrict__ cTB, float* __restrict__ TotA, float* __restrict__ TotB,
        int logD) {
    const int t = threadIdx.x;
    const int lane = t & 63, w = t >> 6;
    const int D = 1 << logD;
    const int col = blockIdx.x * 4 + w;
    const int h = col >> logD, d = col & (D - 1);
    const size_t base = (size_t)h * CH * D + d;
    float vA[8], vB[8];
#pragma unroll
    for (int q = 0; q < 8; q++) {
        size_t o = base + (size_t)(lane * 8 + q) * D;
        vA[q] = cTA[o];
        vB[q] = cTB[o];
    }
    float laA = 0.f, laB = 0.f;
#pragma unroll
    for (int q = 0; q < 8; q++) { laA += vA[q]; laB += vB[q]; }
    float sA = laA, sB = laB;
#pragma unroll
    for (int o = 1; o < 64; o <<= 1) {
        float uA = __shfl_up(sA, o, 64);
        float uB = __shfl_up(sB, o, 64);
        if (lane >= o) { sA += uA; sB += uB; }
    }
    float totA = __shfl(sA, 63, 64);
    float totB = __shfl(sB, 63, 64);
    float runA = sA - laA, runB = sB - laB;
#pragma unroll
    for (int q = 0; q < 8; q++) {
        size_t o = base + (size_t)(lane * 8 + q) * D;
        float tA = vA[q], tB = vB[q];
        cTA[o] = runA;
        cTB[o] = runB;
        runA += tA; runB += tB;
    }
    if (lane == 0) {
        TotA[h * D + d] = totA;
        TotB[h * D + d] = totB;
    }
}

// ---------------- k5: layer-1 scan p3 (fp32 A/B) ----------------
__global__ __launch_bounds__(256) void k5_scan1_p3(const float* __restrict__ Wx1,
        const float* __restrict__ ts1, const int* __restrict__ perm1,
        const float* __restrict__ cTA, const float* __restrict__ cTB,
        const float* __restrict__ TotA,
        float* __restrict__ A, float* __restrict__ B) {
    const int ch = blockIdx.x, t = threadIdx.x;
    const int h = t >> 6, d = t & 63;
    const float tmax = ts1[h * NND + NND - 1];
    float runA = cTA[(h * CH + ch) * D1 + d];
    float runB = cTB[(h * CH + ch) * D1 + d];
    const float totA = TotA[h * D1 + d];
    const int k0 = ch * CHR;
    float v[CHR], wa[CHR], wb[CHR];
#pragma unroll
    for (int r = 0; r < CHR; r++) {
        float u = ts1[h * NND + k0 + r] - tmax;
        wa[r] = __expf(u); wb[r] = __expf(LEAKY * u);
        int j = perm1[h * NND + k0 + r];
        v[r] = Wx1[(size_t)j * HID + h * D1 + d];
    }
#pragma unroll
    for (int r = 0; r < CHR; r++) {
        size_t o = ((size_t)(h * NP1 + k0 + r)) * D1 + d;
        A[o] = totA - runA;
        B[o] = runB;
        runA += wa[r] * v[r];
        runB += wb[r] * v[r];
    }
    if (ch == CH - 1) {
        size_t o = ((size_t)(h * NP1 + NND)) * D1 + d;
        A[o] = totA - runA;
        B[o] = runB;
    }
}

// ---------------- k6: lookup1 -> h1 bf16 k-panels + fused escore2 ----------------
__global__ __launch_bounds__(256) void k6_lookup1(const float* __restrict__ es,
        const float* __restrict__ ts,
        const float* __restrict__ A, const float* __restrict__ Bv,
        const float* __restrict__ SA, const float* __restrict__ SB,
        const float* __restrict__ w_es, const float* __restrict__ w_et,
        unsigned short* __restrict__ h1p,
        float* __restrict__ es2, float* __restrict__ et2) {
    __shared__ float hbuf[256];
    const int i = blockIdx.x, t = threadIdx.x;
    const int h = t >> 6, d = t & 63;
    const int lane = t & 63, wid = t >> 6;
    float c = es[h * NND + i];
    float tmax = ts[h * NND + NND - 1];
    float s = c + tmax;
    float m = (s >= 0.f) ? s : LEAKY * s;
    float al = __expf(s - m);
    float be = __expf(LEAKY * s - m);
    int k = lower_bound_f(ts + h * NND, -c);
    size_t o = ((size_t)(h * NP1 + k)) * D1 + d;
    float num = al * A[o] + be * Bv[o];
    float den = al * SA[h * NP1 + k] + be * SB[h * NP1 + k];
    float val = num / den;
    float hv = (val > 0.f) ? val : expm1f(val);
    h1p[((size_t)(t >> 3) * NND + i) * 8 + (t & 7)] = f2bf(hv);
    hbuf[t] = hv;
    __syncthreads();
    float4 hv4 = *(const float4*)&hbuf[lane * 4];
    float4 we4 = *(const float4*)&w_es[wid * HID + lane * 4];
    float4 wt4 = *(const float4*)&w_et[wid * HID + lane * 4];
    float pes = hv4.x * we4.x + hv4.y * we4.y + hv4.z * we4.z + hv4.w * we4.w;
    float pet = hv4.x * wt4.x + hv4.y * wt4.y + hv4.z * wt4.z + hv4.w * wt4.w;
    pes = wave_sum(pes);
    pet = wave_sum(pet);
    if (lane == 0) {
        es2[wid * NND + i] = pes;
        et2[wid * NND + i] = pet;
    }
}

// ---------------- k7: gemm2 plain-bf16, bf16 Wx2 output | sort2 ----------------
__global__ __launch_bounds__(256) void k7_gemm2_sort2(
        const unsigned short* __restrict__ h1p, const unsigned short* __restrict__ W2p,
        unsigned short* __restrict__ Wx2b,
        const float* __restrict__ et2, float* __restrict__ ts2, int* __restrict__ perm2) {
    union SM7 {
        struct { unsigned short Ah[512][8], Bh[256][8]; } g;
        struct { unsigned key[NND]; int pr[64]; } s;
    };
    __shared__ SM7 sm;
    const int bid = blockIdx.x, t = threadIdx.x;
    if (bid >= 512) {
        sort_block(sm.s.key, sm.s.pr, et2, ts2, perm2,
                   (bid - 512) >> 6, ((bid - 512) & 63) * 64, t);
        return;
    }
    const int lane = t & 63, w = t >> 6;
    const int n0 = (bid & 15) * 64, m0 = (bid >> 4) * 128;
    const int fr = lane & 15, kg = lane >> 4;
    f32x4 z4 = {0.f, 0.f, 0.f, 0.f};
    f32x4 acc[2][4] = {{z4, z4, z4, z4}, {z4, z4, z4, z4}};
    u16x8 rA[2], rB;
    auto load_step = [&](int k0) {
        int kgrp = (k0 >> 3) + w;
#pragma unroll
        for (int rr = 0; rr < 2; rr++)
            rA[rr] = *(const u16x8*)&h1p[((size_t)kgrp * NND + m0 + rr * 64 + lane) * 8];
        rB = *(const u16x8*)&W2p[((size_t)kgrp * C2 + n0 + lane) * 8];
    };
    load_step(0);
    for (int k0 = 0; k0 < HID; k0 += 32) {
#pragma unroll
        for (int rr = 0; rr < 2; rr++)
            *(u16x8*)&sm.g.Ah[w * 128 + rr * 64 + lane][0] = rA[rr];
        *(u16x8*)&sm.g.Bh[w * 64 + lane][0] = rB;
        __syncthreads();
        if (k0 + 32 < HID) load_step(k0 + 32);
        bf16x8 ah[2], bh[4];
#pragma unroll
        for (int mb = 0; mb < 2; mb++)
            ah[mb] = *(bf16x8*)&sm.g.Ah[kg * 128 + w * 32 + mb * 16 + fr][0];
#pragma unroll
        for (int nb = 0; nb < 4; nb++)
            bh[nb] = *(bf16x8*)&sm.g.Bh[kg * 64 + nb * 16 + fr][0];
#pragma unroll
        for (int mb = 0; mb < 2; mb++)
#pragma unroll
            for (int nb = 0; nb < 4; nb++)
                MM(ah[mb], bh[nb], acc[mb][nb]);
        __syncthreads();
    }
#pragma unroll
    for (int mb = 0; mb < 2; mb++)
#pragma unroll
        for (int r = 0; r < 4; r++) {
            int row = m0 + w * 32 + mb * 16 + kg * 4 + r;
#pragma unroll
            for (int nb = 0; nb < 4; nb++)
                Wx2b[(size_t)row * C2 + n0 + nb * 16 + fr] = f2bf(acc[mb][nb][r]);
        }
}

// ---------------- k8: layer-2 scan p1 (bf16 Wx2) + wprep2 ----------------
__global__ __launch_bounds__(256) void k8_scan2_p1(const unsigned short* __restrict__ Wx2b,
        const float* __restrict__ ts2, const int* __restrict__ perm2,
        float* __restrict__ cTA, float* __restrict__ cTB,
        float* __restrict__ SA, float* __restrict__ SB) {
    __shared__ float swA[4], swB[4];
    const int bid = blockIdx.x, t = threadIdx.x;
    if (bid >= 2048) { wprep_block(ts2, SA, SB, bid - 2048, t, swA, swB); return; }
    const int ch = bid & (CH - 1), h = bid >> 9;
    const int d = t, k0 = ch * CHR;
    const float tmax = ts2[h * NND + NND - 1];
    float aA = 0.f, aB = 0.f;
#pragma unroll
    for (int r = 0; r < CHR; r++) {
        float u = ts2[h * NND + k0 + r] - tmax;
        float wa = __expf(u), wb = __expf(LEAKY * u);
        int j = perm2[h * NND + k0 + r];
        float v = bf2f(Wx2b[(size_t)j * C2 + h * D2 + d]);
        aA += wa * v; aB += wb * v;
    }
    cTA[(h * CH + ch) * D2 + d] = aA;
    cTB[(h * CH + ch) * D2 + d] = aB;
}

// ---------------- k10: layer-2 scan p3 (bf16 Wx2) -> packed bf16 (A | B<<16) -------------
__global__ __launch_bounds__(256) void k10_scan2_p3(const unsigned short* __restrict__ Wx2b,
        const float* __restrict__ ts2, const int* __restrict__ perm2,
        const float* __restrict__ cTA, const float* __restrict__ cTB,
        const float* __restrict__ TotA,
        unsigned* __restrict__ AB) {
    const int bid = blockIdx.x, t = threadIdx.x;
    const int ch = bid & (CH - 1), h = bid >> 9;
    const int d = t;
    const float tmax = ts2[h * NND + NND - 1];
    float runA = cTA[(h * CH + ch) * D2 + d];
    float runB = cTB[(h * CH + ch) * D2 + d];
    const float totA = TotA[h * D2 + d];
    const int k0 = ch * CHR;
    float v[CHR], wa[CHR], wb[CHR];
#pragma unroll
    for (int r = 0; r < CHR; r++) {
        float u = ts2[h * NND + k0 + r] - tmax;
        wa[r] = __expf(u); wb[r] = __expf(LEAKY * u);
        int j = perm2[h * NND + k0 + r];
        v[r] = bf2f(Wx2b[(size_t)j * C2 + h * D2 + d]);
    }
#pragma unroll
    for (int r = 0; r < CHR; r++) {
        size_t o = ((size_t)(h * NP1 + k0 + r)) * D2 + d;
        AB[o] = (unsigned)f2bf(totA - runA) | ((unsigned)f2bf(runB) << 16);
        runA += wa[r] * v[r];
        runB += wb[r] * v[r];
    }
    if (ch == CH - 1) {
        size_t o = ((size_t)(h * NP1 + NND)) * D2 + d;
        AB[o] = (unsigned)f2bf(totA - runA) | ((unsigned)f2bf(runB) << 16);
    }
}

// ---------------- k11: lookup2 (packed A/B; head-mean + ELU + LayerNorm) ----------------
__global__ __launch_bounds__(256) void k11_lookup2(const float* __restrict__ es,
        const float* __restrict__ ts,
        const unsigned* __restrict__ AB,
        const float* __restrict__ SA, const float* __restrict__ SB,
        const float* __restrict__ gamma, const float* __restrict__ betap,
        float* __restrict__ out) {
    __shared__ float red[4];
    const int i = blockIdx.x;
    const int t = threadIdx.x;
    const int wid = t >> 6, lane = t & 63;
    float acc = 0.f;
#pragma unroll
    for (int h = 0; h < HEADS; h++) {
        float c = es[h * NND + i];
        float tmax = ts[h * NND + NND - 1];
        float s = c + tmax;
        float m = (s >= 0.f) ? s : LEAKY * s;
        float al = __expf(s - m);
        float be = __expf(LEAKY * s - m);
        int k = lower_bound_f(ts + h * NND, -c);
        size_t o = ((size_t)(h * NP1 + k)) * D2 + t;
        unsigned u = AB[o];
        float Av = bf2f((unsigned short)(u & 0xFFFFu));
        float Bu = bf2f((unsigned short)(u >> 16));
        float num = al * Av + be * Bu;
        float den = al * SA[h * NP1 + k] + be * SB[h * NP1 + k];
        acc += num / den;
    }
    acc *= 0.25f;
    float xv = (acc > 0.f) ? acc : expm1f(acc);
    float sv = wave_sum(xv);
    if (lane == 0) red[wid] = sv;
    __syncthreads();
    float mu = (red[0] + red[1] + red[2] + red[3]) * (1.f / 256.f);
    __syncthreads();
    float dv = xv - mu;
    float s2 = wave_sum(dv * dv);
    if (lane == 0) red[wid] = s2;
    __syncthreads();
    float var = (red[0] + red[1] + red[2] + red[3]) * (1.f / 256.f);
    out[i * D2 + t] = gamma[t] * dv * rsqrtf(var + LN_EPS) + betap[t];
}

extern "C" void kernel_launch(void* const* d_in, const int* in_sizes, int n_in,
                              void* d_out, int out_size, void* d_ws, size_t ws_size,
                              hipStream_t stream) {
    const float* x     = (const float*)d_in[0];
    const float* W1    = (const float*)d_in[1];
    const float* attn1 = (const float*)d_in[2];
    const float* W2    = (const float*)d_in[3];
    const float* attn2 = (const float*)d_in[4];
    const float* gamma = (const float*)d_in[5];
    const float* betap = (const float*)d_in[6];
    float* out = (float*)d_out;

    char* ws = (char*)d_ws;
    size_t off = 0;
    auto alloc = [&](size_t nbytes) -> void* {
        void* p = (void*)(ws + off);
        off += (nbytes + 255) & ~(size_t)255;
        return p;
    };

    float* Wx1 = (float*)alloc((size_t)NND * HID * 4);
    unsigned short* Wx2b = (unsigned short*)alloc((size_t)NND * C2 * 2);
    unsigned short* h1p = (unsigned short*)alloc((size_t)NND * HID * 2);
    float* es1 = (float*)alloc((size_t)HEADS * NND * 4);
    float* et1 = (float*)alloc((size_t)HEADS * NND * 4);
    float* es2 = (float*)alloc((size_t)HEADS * NND * 4);
    float* et2 = (float*)alloc((size_t)HEADS * NND * 4);
    float* ts1 = (float*)alloc((size_t)HEADS * NND * 4);
    float* ts2 = (float*)alloc((size_t)HEADS * NND * 4);
    int* perm1 = (int*)alloc((size_t)HEADS * NND * 4);
    int* perm2 = (int*)alloc((size_t)HEADS * NND * 4);
    float* A   = (float*)alloc((size_t)HEADS * NP1 * D1 * 4);
    float* B   = (float*)alloc((size_t)HEADS * NP1 * D1 * 4);
    unsigned* AB2 = (unsigned*)alloc((size_t)HEADS * NP1 * D2 * 4);
    float* SA  = (float*)alloc((size_t)HEADS * NP1 * 4);
    float* SB  = (float*)alloc((size_t)HEADS * NP1 * 4);
    float* cTA = (float*)alloc((size_t)HEADS * CH * D2 * 4);
    float* cTB = (float*)alloc((size_t)HEADS * CH * D2 * 4);
    float* TotA = (float*)alloc((size_t)HEADS * D2 * 4);
    float* TotB = (float*)alloc((size_t)HEADS * D2 * 4);
    unsigned short* W2p = (unsigned short*)alloc((size_t)262144 * 2);
    float* w_es = (float*)alloc((size_t)HEADS * HID * 4);
    float* w_et = (float*)alloc((size_t)HEADS * HID * 4);
    (void)ws_size; (void)in_sizes; (void)n_in; (void)out_size;

    // ---- layer 1 ----
    k1_gemm1_prep<<<832, 256, 0, stream>>>(x, W1, attn1, W2, attn2,
                                           Wx1, es1, et1, W2p, w_es, w_et);
    k2_sort<<<256, 256, 0, stream>>>(et1, ts1, perm1);
    k3_scan1_p1<<<CH + 4, 256, 0, stream>>>(Wx1, ts1, perm1, cTA, cTB, SA, SB);
    k_scan_p2<<<64, 256, 0, stream>>>(cTA, cTB, TotA, TotB, 6);
    k5_scan1_p3<<<CH, 256, 0, stream>>>(Wx1, ts1, perm1, cTA, cTB, TotA, A, B);
    k6_lookup1<<<NND, 256, 0, stream>>>(es1, ts1, A, B, SA, SB, w_es, w_et,
                                        h1p, es2, et2);

    // ---- layer 2 ----
    k7_gemm2_sort2<<<768, 256, 0, stream>>>(h1p, W2p, Wx2b, et2, ts2, perm2);
    k8_scan2_p1<<<2052, 256, 0, stream>>>(Wx2b, ts2, perm2, cTA, cTB, SA, SB);
    k_scan_p2<<<256, 256, 0, stream>>>(cTA, cTB, TotA, TotB, 8);
    k10_scan2_p3<<<2048, 256, 0, stream>>>(Wx2b, ts2, perm2, cTA, cTB, TotA, AB2);
    k11_lookup2<<<NND, 256, 0, stream>>>(es2, ts2, AB2, SA, SB, gamma, betap, out);
}